// Round 6
// baseline (786.505 us; speedup 1.0000x reference)
//
#include <hip/hip_runtime.h>

#define N_NODES 50000
#define N_EDGES 800000
#define D 128
#define C_OUT 10
#define BN_EPS 1e-5f
#define SCAN_BLOCKS 196   // ceil(50000/256)

typedef unsigned int uint32;
typedef __attribute__((ext_vector_type(8))) short bf16x8;
typedef __attribute__((ext_vector_type(4))) float f32x4;

__device__ __forceinline__ float bf2f(unsigned int u16) {
    unsigned int x = u16 << 16;
    float f;
    __builtin_memcpy(&f, &x, 4);
    return f;
}
__device__ __forceinline__ unsigned int f2bf(float f) {
    unsigned int x;
    __builtin_memcpy(&x, &f, 4);
    unsigned int r = x + 0x7FFFu + ((x >> 16) & 1u);  // RNE
    return r >> 16;
}

// ---------------- adjacency: linked-list build, ONE chain walk -> CSR ----------------
// R3: random 4B scatter = 54MB writeback (16x amplification). R4: chain-traverse
// per layer = 100MB extra reads x3. This pays chain cost once; CSR segments are
// written sequentially per thread so L2 merges writebacks (~3.4MB).

__global__ void k_init(int* deg, int* head, float* sums) {
    int i = blockIdx.x * blockDim.x + threadIdx.x;
    if (i < N_NODES) { deg[i] = 1; head[i] = -1; }  // deg=1: self loop
    if (i < 768) sums[i] = 0.0f;                    // 3 layers x (sum|sumsq)
}

__global__ void k_link(const int* __restrict__ ei, int* __restrict__ deg,
                       int* __restrict__ head, int* __restrict__ next) {
    int e = blockIdx.x * blockDim.x + threadIdx.x;
    if (e >= N_EDGES) return;
    int d = ei[N_EDGES + e];                 // destination (col)
    atomicAdd(&deg[d], 1);
    int old = atomicExch(&head[d], e);
    next[e] = old;                           // sequential 3.2MB stream
}

__global__ __launch_bounds__(256) void k_scan1(const int* __restrict__ deg,
                                               int* __restrict__ offsets,
                                               int* __restrict__ blocksum,
                                               float* __restrict__ dinv) {
    __shared__ int sm[256];
    int tid = threadIdx.x;
    int i = blockIdx.x * 256 + tid;
    int v = (i < N_NODES) ? deg[i] : 0;
    if (i < N_NODES) dinv[i] = rsqrtf((float)v);
    sm[tid] = v;
    __syncthreads();
    for (int off = 1; off < 256; off <<= 1) {
        int t = (tid >= off) ? sm[tid - off] : 0;
        __syncthreads();
        sm[tid] += t;
        __syncthreads();
    }
    if (i < N_NODES) offsets[i] = sm[tid] - v;
    if (tid == 255) blocksum[blockIdx.x] = sm[255];
}

__global__ __launch_bounds__(256) void k_scan2(int* __restrict__ blocksum,
                                               int* __restrict__ offsets) {
    __shared__ int sm[256];
    int tid = threadIdx.x;
    int v = (tid < SCAN_BLOCKS) ? blocksum[tid] : 0;
    sm[tid] = v;
    __syncthreads();
    for (int off = 1; off < 256; off <<= 1) {
        int t = (tid >= off) ? sm[tid - off] : 0;
        __syncthreads();
        sm[tid] += t;
        __syncthreads();
    }
    if (tid < SCAN_BLOCKS) blocksum[tid] = sm[tid] - v;
    if (tid == 255) offsets[N_NODES] = sm[255];
}

__global__ __launch_bounds__(256) void k_scan3(int* __restrict__ offsets,
                                               const int* __restrict__ blocksum) {
    int i = blockIdx.x * 256 + threadIdx.x;
    if (i < N_NODES) offsets[i] += blocksum[blockIdx.x];
}

// chain walk: thread-per-node, write own CSR segment sequentially (L2-merged)
__global__ void k_c2csr(const int* __restrict__ ei, const int* __restrict__ head,
                        const int* __restrict__ next, const int* __restrict__ offsets,
                        int* __restrict__ csr_src) {
    int i = blockIdx.x * blockDim.x + threadIdx.x;
    if (i >= N_NODES) return;
    int off = offsets[i];
    csr_src[off++] = i;              // self loop first
    int e = head[i];
    while (e >= 0) {
        csr_src[off++] = ei[e];      // source id directly
        e = next[e];
    }
}

// ---------------- W prep: fp32 [k][n] -> bf16 transposed [n][k] ----------------

__global__ void k_prep(const float* __restrict__ W1, const float* __restrict__ W2,
                       const float* __restrict__ W3, unsigned short* __restrict__ WT) {
    int mat = blockIdx.x >> 7;
    int n = blockIdx.x & 127;
    int k = threadIdx.x;  // 128 threads
    const float* W = (mat == 0) ? W1 : ((mat == 1) ? W2 : W3);
    WT[mat * 16384 + n * 128 + k] = (unsigned short)f2bf(W[k * 128 + n]);
}

// Wf slices 0,1 (for fused readout in gemm2/gemm3): bf16 [li][n(16, pad0)][k(128)]
__global__ void k_prepf(const float* __restrict__ Wf, unsigned short* __restrict__ WfT) {
    int idx = blockIdx.x * 256 + threadIdx.x;   // 4096 total
    if (idx >= 4096) return;
    int li = idx >> 11, rem = idx & 2047;
    int n = rem >> 7, k = rem & 127;
    WfT[idx] = (n < C_OUT) ? (unsigned short)f2bf(Wf[(li * 128 + k) * C_OUT + n]) : 0;
}

// ---------------- MFMA GEMM + fused BN-prologue + fused readout partial ----------
// hl[M,128](bf16, row-scaled by dinv) = bnrelu(A) @ W ; optionally
// out[M,10] (=|+=) bnrelu(A) @ WfT-slice (+ bias). mode: 0=none, 1=write+bias, 2=accum.

__global__ __launch_bounds__(256) void k_gemm(const float* __restrict__ A,
                                              const unsigned short* __restrict__ WT,
                                              unsigned short* __restrict__ hl,
                                              const float* __restrict__ sums,
                                              const float* __restrict__ g,
                                              const float* __restrict__ be,
                                              const float* __restrict__ dinvp,
                                              const unsigned short* __restrict__ WfT,
                                              const float* __restrict__ bfv,
                                              float* __restrict__ outp, int mode) {
    __shared__ unsigned short As[128 * 128];  // 32 KB
    __shared__ unsigned short Ws[128 * 128];  // 32 KB
    int tid = threadIdx.x;
    int row0 = blockIdx.x * 128;

    // per-thread BN scale/shift: this thread only stages columns cc..cc+3
    int cc = (tid & 31) * 4;
    float4 s4 = make_float4(1.f, 1.f, 1.f, 1.f);
    float4 t4 = make_float4(0.f, 0.f, 0.f, 0.f);
    if (sums) {
        float4 sm_ = *(const float4*)&sums[cc];
        float4 sq_ = *(const float4*)&sums[128 + cc];
        float4 gg = *(const float4*)&g[cc];
        float4 bb = *(const float4*)&be[cc];
        float m0 = sm_.x * (1.0f / N_NODES), m1 = sm_.y * (1.0f / N_NODES);
        float m2 = sm_.z * (1.0f / N_NODES), m3 = sm_.w * (1.0f / N_NODES);
        s4.x = gg.x * rsqrtf(fmaxf(sq_.x * (1.0f / N_NODES) - m0 * m0, 0.f) + BN_EPS);
        s4.y = gg.y * rsqrtf(fmaxf(sq_.y * (1.0f / N_NODES) - m1 * m1, 0.f) + BN_EPS);
        s4.z = gg.z * rsqrtf(fmaxf(sq_.z * (1.0f / N_NODES) - m2 * m2, 0.f) + BN_EPS);
        s4.w = gg.w * rsqrtf(fmaxf(sq_.w * (1.0f / N_NODES) - m3 * m3, 0.f) + BN_EPS);
        t4.x = bb.x - m0 * s4.x;  t4.y = bb.y - m1 * s4.y;
        t4.z = bb.z - m2 * s4.z;  t4.w = bb.w - m3 * s4.w;
    }

    // stage Ws (bf16 W^T [n][k]); XOR swizzle in 16B blocks: 2-way conflicts max (free)
    const ushort4* WT4 = (const ushort4*)WT;
#pragma unroll
    for (int i = 0; i < 16; ++i) {
        int idx = i * 256 + tid;
        int r = idx >> 5, c4 = idx & 31;
        ushort4 v = WT4[idx];
        int swz = (c4 >> 1) ^ (r & 15);
        *(ushort4*)&Ws[r * 128 + swz * 8 + (c4 & 1) * 4] = v;
    }
    // stage As: fp32 read, optional BN+ReLU, cvt bf16, swizzled write
    const float4* A4 = (const float4*)A;
#pragma unroll
    for (int i = 0; i < 16; ++i) {
        int idx = i * 256 + tid;
        int r = idx >> 5, c4 = idx & 31;
        int gr = row0 + r;
        float4 v = make_float4(0.f, 0.f, 0.f, 0.f);
        if (gr < N_NODES) v = A4[(size_t)gr * 32 + c4];
        if (sums) {
            v.x = fmaxf(v.x * s4.x + t4.x, 0.f);
            v.y = fmaxf(v.y * s4.y + t4.y, 0.f);
            v.z = fmaxf(v.z * s4.z + t4.z, 0.f);
            v.w = fmaxf(v.w * s4.w + t4.w, 0.f);
        }
        ushort4 o;
        o.x = (unsigned short)f2bf(v.x);
        o.y = (unsigned short)f2bf(v.y);
        o.z = (unsigned short)f2bf(v.z);
        o.w = (unsigned short)f2bf(v.w);
        int swz = (c4 >> 1) ^ (r & 15);
        *(ushort4*)&As[r * 128 + swz * 8 + (c4 & 1) * 4] = o;
    }
    __syncthreads();

    int wave = tid >> 6, lane = tid & 63;
    int quad = lane >> 4, l16 = lane & 15;
    int m0 = wave * 32;

    // a-frags: A[m=lane&15][k = ks*32 + quad*8 + j]
    bf16x8 af[2][4];
#pragma unroll
    for (int mt = 0; mt < 2; ++mt) {
        int m = m0 + mt * 16 + l16;
#pragma unroll
        for (int ks = 0; ks < 4; ++ks) {
            int swz = (ks * 4 + quad) ^ (m & 15);
            af[mt][ks] = *(bf16x8*)&As[m * 128 + swz * 8];
        }
    }

    f32x4 acc[8][2];
#pragma unroll
    for (int nt = 0; nt < 8; ++nt)
#pragma unroll
        for (int mt = 0; mt < 2; ++mt) acc[nt][mt] = (f32x4){0.f, 0.f, 0.f, 0.f};

#pragma unroll
    for (int nt = 0; nt < 8; ++nt) {
        int n = nt * 16 + l16;
        bf16x8 bfr[4];
#pragma unroll
        for (int ks = 0; ks < 4; ++ks) {
            int swz = (ks * 4 + quad) ^ (n & 15);
            bfr[ks] = *(bf16x8*)&Ws[n * 128 + swz * 8];
        }
#pragma unroll
        for (int mt = 0; mt < 2; ++mt)
#pragma unroll
            for (int ks = 0; ks < 4; ++ks)
                acc[nt][mt] = __builtin_amdgcn_mfma_f32_16x16x32_bf16(
                    af[mt][ks], bfr[ks], acc[nt][mt], 0, 0, 0);
    }

    // fused readout partial: out (=|+=) h_staged @ WfT (+bias). 8 extra MFMAs.
    if (mode != 0) {
        f32x4 accO[2] = {(f32x4){0.f, 0.f, 0.f, 0.f}, (f32x4){0.f, 0.f, 0.f, 0.f}};
#pragma unroll
        for (int ks = 0; ks < 4; ++ks) {
            int chunk = ks * 4 + quad;
            bf16x8 bw = *(const bf16x8*)&WfT[l16 * 128 + chunk * 8];  // tiny, L2-hot
            accO[0] = __builtin_amdgcn_mfma_f32_16x16x32_bf16(af[0][ks], bw, accO[0], 0, 0, 0);
            accO[1] = __builtin_amdgcn_mfma_f32_16x16x32_bf16(af[1][ks], bw, accO[1], 0, 0, 0);
        }
        if (l16 < C_OUT) {
#pragma unroll
            for (int mt = 0; mt < 2; ++mt)
#pragma unroll
                for (int reg = 0; reg < 4; ++reg) {
                    int m = row0 + m0 + mt * 16 + quad * 4 + reg;
                    if (m < N_NODES) {
                        size_t o = (size_t)m * C_OUT + l16;
                        float v = accO[mt][reg];
                        if (mode == 1) outp[o] = v + bfv[l16];
                        else outp[o] += v;
                    }
                }
        }
    }

    // C/D: col = lane&15, row = quad*4 + reg; scale by dinv, store bf16
#pragma unroll
    for (int mt = 0; mt < 2; ++mt) {
#pragma unroll
        for (int reg = 0; reg < 4; ++reg) {
            int m = row0 + m0 + mt * 16 + quad * 4 + reg;
            if (m < N_NODES) {
                float di = dinvp[m];
#pragma unroll
                for (int nt = 0; nt < 8; ++nt) {
                    int n = nt * 16 + l16;
                    hl[(size_t)m * 128 + n] = (unsigned short)f2bf(acc[nt][mt][reg] * di);
                }
            }
        }
    }
}

// ---------------- Aggregation + fused BN stats ----------------
// 1024 threads = 16 nodes/block; 3125 blocks x 16 = 50000 exactly (no tail).
// Per-block LDS reduction -> 256 atomics/block.

__global__ __launch_bounds__(1024) void k_agg(const unsigned short* __restrict__ hl,
                                              const int* __restrict__ csr_src,
                                              const int* __restrict__ offsets,
                                              const float* __restrict__ dinv,
                                              float* __restrict__ agg,
                                              float* __restrict__ sums) {
    __shared__ float red[4][16][64];   // [stat-comp][wave][lane], 16KB
    int tid = threadIdx.x;
    int wave = tid >> 6, lane = tid & 63;
    int node = blockIdx.x * 16 + wave;          // always < N_NODES
    int beg = offsets[node], end = offsets[node + 1];
    float ax = 0.f, ay = 0.f;
    int e = beg;
    for (; e + 1 < end; e += 2) {
        int j0 = csr_src[e];
        int j1 = csr_src[e + 1];
        uint32 p0 = *(const uint32*)&hl[(size_t)j0 * 128 + lane * 2];
        uint32 p1 = *(const uint32*)&hl[(size_t)j1 * 128 + lane * 2];
        ax += bf2f(p0 & 0xFFFFu) + bf2f(p1 & 0xFFFFu);
        ay += bf2f(p0 >> 16) + bf2f(p1 >> 16);
    }
    if (e < end) {
        int j = csr_src[e];
        uint32 p = *(const uint32*)&hl[(size_t)j * 128 + lane * 2];
        ax += bf2f(p & 0xFFFFu);
        ay += bf2f(p >> 16);
    }
    float di = dinv[node];
    float vx = ax * di, vy = ay * di;
    *(float2*)&agg[(size_t)node * 128 + lane * 2] = make_float2(vx, vy);
    red[0][wave][lane] = vx;
    red[1][wave][lane] = vx * vx;
    red[2][wave][lane] = vy;
    red[3][wave][lane] = vy * vy;
    __syncthreads();
    if (tid < 256) {
        int l = tid & 63, c = tid >> 6;   // c: 0=sum(2l) 1=sq(2l) 2=sum(2l+1) 3=sq(2l+1)
        float s = 0.f;
#pragma unroll
        for (int w = 0; w < 16; ++w) s += red[c][w][l];
        atomicAdd(&sums[(c & 1) * 128 + 2 * l + (c >> 1)], s);
    }
}

// ---------------- Final readout (layer 3 only): out += bnrelu(h) @ Wf[256:384,:] ----

__global__ void k_out(const float* __restrict__ h, const float* __restrict__ Wf,
                      float* __restrict__ out, int base,
                      const float* __restrict__ sums,
                      const float* __restrict__ g, const float* __restrict__ be) {
    __shared__ float Wl[128 * C_OUT];
    __shared__ float scl[128], shl[128];
    int tid = threadIdx.x;
    for (int i = tid; i < 128 * C_OUT; i += 256) Wl[i] = Wf[base * C_OUT + i];
    if (tid < 128) {
        float mean = sums[tid] * (1.0f / N_NODES);
        float var = fmaxf(sums[128 + tid] * (1.0f / N_NODES) - mean * mean, 0.f);
        float s = g[tid] * rsqrtf(var + BN_EPS);
        scl[tid] = s;
        shl[tid] = be[tid] - mean * s;
    }
    __syncthreads();
    int node = blockIdx.x * 4 + (tid >> 6);
    if (node >= N_NODES) return;
    int lane = tid & 63;
    float acc[C_OUT];
#pragma unroll
    for (int o = 0; o < C_OUT; ++o) acc[o] = 0.f;
#pragma unroll
    for (int t = 0; t < 128; t += 64) {
        int c = t + lane;
        float v = h[(size_t)node * 128 + c];
        v = fmaxf(v * scl[c] + shl[c], 0.f);
#pragma unroll
        for (int o = 0; o < C_OUT; ++o) acc[o] += v * Wl[c * C_OUT + o];
    }
#pragma unroll
    for (int s = 32; s > 0; s >>= 1) {
#pragma unroll
        for (int o = 0; o < C_OUT; ++o) acc[o] += __shfl_down(acc[o], s, 64);
    }
    if (lane == 0) {
#pragma unroll
        for (int o = 0; o < C_OUT; ++o)
            out[(size_t)node * C_OUT + o] += acc[o];
    }
}

// ---------------- launch ----------------

extern "C" void kernel_launch(void* const* d_in, const int* in_sizes, int n_in,
                              void* d_out, int out_size, void* d_ws, size_t ws_size,
                              hipStream_t stream) {
    const float* x  = (const float*)d_in[0];
    const int*   ei = (const int*)d_in[1];
    const float* W1 = (const float*)d_in[2];
    const float* W2 = (const float*)d_in[4];
    const float* W3 = (const float*)d_in[6];
    // b1/b2/b3 absorbed exactly by BN mean-subtraction
    const float* g1  = (const float*)d_in[8];
    const float* be1 = (const float*)d_in[9];
    const float* g2  = (const float*)d_in[10];
    const float* be2 = (const float*)d_in[11];
    const float* g3  = (const float*)d_in[12];
    const float* be3 = (const float*)d_in[13];
    const float* Wf  = (const float*)d_in[14];
    const float* bf  = (const float*)d_in[15];
    float* out = (float*)d_out;

    char* ws = (char*)d_ws;
    size_t off = 0;
    auto alloc = [&](size_t bytes) -> void* {
        void* p = ws + off;
        off = (off + bytes + 255) & ~(size_t)255;
        return p;
    };
    int*   deg      = (int*)alloc((size_t)N_NODES * 4);
    int*   head     = (int*)alloc((size_t)N_NODES * 4);
    int*   next     = (int*)alloc((size_t)N_EDGES * 4);
    int*   offsets  = (int*)alloc((size_t)(N_NODES + 1) * 4);
    int*   blocksum = (int*)alloc((size_t)SCAN_BLOCKS * 4);
    int*   csr_src  = (int*)alloc((size_t)(N_EDGES + N_NODES) * 4);
    float* dinv     = (float*)alloc((size_t)N_NODES * 4);
    float* sums     = (float*)alloc(768 * 4);
    unsigned short* WT  = (unsigned short*)alloc((size_t)3 * 128 * 128 * 2);
    unsigned short* WfT = (unsigned short*)alloc((size_t)2 * 16 * 128 * 2);
    unsigned short* hl  = (unsigned short*)alloc((size_t)N_NODES * 128 * 2);
    float* bufA    = (float*)alloc((size_t)N_NODES * 128 * 4);
    float* bufB    = (float*)alloc((size_t)N_NODES * 128 * 4);

    const int TPB = 256;
    k_prep<<<384, 128, 0, stream>>>(W1, W2, W3, WT);
    k_prepf<<<16, 256, 0, stream>>>(Wf, WfT);
    k_init<<<(N_NODES + TPB - 1) / TPB, TPB, 0, stream>>>(deg, head, sums);
    k_link<<<(N_EDGES + TPB - 1) / TPB, TPB, 0, stream>>>(ei, deg, head, next);
    k_scan1<<<SCAN_BLOCKS, 256, 0, stream>>>(deg, offsets, blocksum, dinv);
    k_scan2<<<1, 256, 0, stream>>>(blocksum, offsets);
    k_scan3<<<SCAN_BLOCKS, 256, 0, stream>>>(offsets, blocksum);
    k_c2csr<<<SCAN_BLOCKS, 256, 0, stream>>>(ei, head, next, offsets, csr_src);

    const int gemm_grid = (N_NODES + 127) / 128;        // 391
    const int agg_grid  = N_NODES / 16;                 // 3125, exact
    const int out_grid  = (N_NODES + 3) / 4;

    // ---- layer 1 ----
    k_gemm<<<gemm_grid, 256, 0, stream>>>(x, WT, hl, nullptr, nullptr, nullptr, dinv,
                                          nullptr, nullptr, nullptr, 0);
    k_agg<<<agg_grid, 1024, 0, stream>>>(hl, csr_src, offsets, dinv, bufA, sums + 0);

    // ---- layer 2 (gemm also emits out = h1 @ Wf0 + bf) ----
    k_gemm<<<gemm_grid, 256, 0, stream>>>(bufA, WT + 16384, hl, sums + 0, g1, be1, dinv,
                                          WfT, bf, out, 1);
    k_agg<<<agg_grid, 1024, 0, stream>>>(hl, csr_src, offsets, dinv, bufB, sums + 256);

    // ---- layer 3 (gemm also emits out += h2 @ Wf1) ----
    k_gemm<<<gemm_grid, 256, 0, stream>>>(bufB, WT + 32768, hl, sums + 256, g2, be2, dinv,
                                          WfT + 2048, nullptr, out, 2);
    k_agg<<<agg_grid, 1024, 0, stream>>>(hl, csr_src, offsets, dinv, bufA, sums + 512);

    // ---- layer 3 readout (fp32) ----
    k_out<<<out_grid, 256, 0, stream>>>(bufA, Wf, out, 256, sums + 512, g3, be3);
}

// Round 7
// 525.051 us; speedup vs baseline: 1.4980x; 1.4980x over previous
//
#include <hip/hip_runtime.h>

#define N_NODES 50000
#define N_EDGES 800000
#define D 128
#define C_OUT 10
#define BN_EPS 1e-5f
#define SCAN_BLOCKS 196   // ceil(50000/256)

typedef unsigned int uint32;
typedef __attribute__((ext_vector_type(8))) short bf16x8;
typedef __attribute__((ext_vector_type(4))) float f32x4;

__device__ __forceinline__ float bf2f(unsigned int u16) {
    unsigned int x = u16 << 16;
    float f;
    __builtin_memcpy(&f, &x, 4);
    return f;
}
__device__ __forceinline__ unsigned int f2bf(float f) {
    unsigned int x;
    __builtin_memcpy(&x, &f, 4);
    unsigned int r = x + 0x7FFFu + ((x >> 16) & 1u);  // RNE
    return r >> 16;
}

// ---------------- adjacency: linked-list build, ONE chain walk -> CSR ----------------
// R3: random 4B scatter = 54MB writeback (16x amplification). R4: chain-traverse
// per layer = 100MB extra reads x3. Pay chain cost once; CSR segments written
// sequentially per thread so L2 merges writebacks.

__global__ void k_init(int* deg, int* head, float* sums) {
    int i = blockIdx.x * blockDim.x + threadIdx.x;
    if (i < N_NODES) { deg[i] = 1; head[i] = -1; }  // deg=1: self loop
    if (i < 768) sums[i] = 0.0f;                    // 3 layers x (sum|sumsq)
}

__global__ void k_link(const int* __restrict__ ei, int* __restrict__ deg,
                       int* __restrict__ head, int* __restrict__ next) {
    int e = blockIdx.x * blockDim.x + threadIdx.x;
    if (e >= N_EDGES) return;
    int d = ei[N_EDGES + e];                 // destination (col)
    atomicAdd(&deg[d], 1);
    int old = atomicExch(&head[d], e);
    next[e] = old;                           // sequential 3.2MB stream
}

__global__ __launch_bounds__(256) void k_scan1(const int* __restrict__ deg,
                                               int* __restrict__ offsets,
                                               int* __restrict__ blocksum,
                                               float* __restrict__ dinv) {
    __shared__ int sm[256];
    int tid = threadIdx.x;
    int i = blockIdx.x * 256 + tid;
    int v = (i < N_NODES) ? deg[i] : 0;
    if (i < N_NODES) dinv[i] = rsqrtf((float)v);
    sm[tid] = v;
    __syncthreads();
    for (int off = 1; off < 256; off <<= 1) {
        int t = (tid >= off) ? sm[tid - off] : 0;
        __syncthreads();
        sm[tid] += t;
        __syncthreads();
    }
    if (i < N_NODES) offsets[i] = sm[tid] - v;
    if (tid == 255) blocksum[blockIdx.x] = sm[255];
}

__global__ __launch_bounds__(256) void k_scan2(int* __restrict__ blocksum,
                                               int* __restrict__ offsets) {
    __shared__ int sm[256];
    int tid = threadIdx.x;
    int v = (tid < SCAN_BLOCKS) ? blocksum[tid] : 0;
    sm[tid] = v;
    __syncthreads();
    for (int off = 1; off < 256; off <<= 1) {
        int t = (tid >= off) ? sm[tid - off] : 0;
        __syncthreads();
        sm[tid] += t;
        __syncthreads();
    }
    if (tid < SCAN_BLOCKS) blocksum[tid] = sm[tid] - v;
    if (tid == 255) offsets[N_NODES] = sm[255];
}

__global__ __launch_bounds__(256) void k_scan3(int* __restrict__ offsets,
                                               const int* __restrict__ blocksum) {
    int i = blockIdx.x * 256 + threadIdx.x;
    if (i < N_NODES) offsets[i] += blocksum[blockIdx.x];
}

// chain walk: thread-per-node, write own CSR segment sequentially (L2-merged)
__global__ void k_c2csr(const int* __restrict__ ei, const int* __restrict__ head,
                        const int* __restrict__ next, const int* __restrict__ offsets,
                        int* __restrict__ csr_src) {
    int i = blockIdx.x * blockDim.x + threadIdx.x;
    if (i >= N_NODES) return;
    int off = offsets[i];
    csr_src[off++] = i;              // self loop first
    int e = head[i];
    while (e >= 0) {
        csr_src[off++] = ei[e];      // source id directly
        e = next[e];
    }
}

// ---------------- W prep: fp32 [k][n] -> bf16 transposed [n][k] ----------------

__global__ void k_prep(const float* __restrict__ W1, const float* __restrict__ W2,
                       const float* __restrict__ W3, unsigned short* __restrict__ WT) {
    int mat = blockIdx.x >> 7;
    int n = blockIdx.x & 127;
    int k = threadIdx.x;  // 128 threads
    const float* W = (mat == 0) ? W1 : ((mat == 1) ? W2 : W3);
    WT[mat * 16384 + n * 128 + k] = (unsigned short)f2bf(W[k * 128 + n]);
}

// Wf slices 0,1 (for fused readout in gemm2/gemm3): bf16 [li][n(16, pad0)][k(128)]
__global__ void k_prepf(const float* __restrict__ Wf, unsigned short* __restrict__ WfT) {
    int idx = blockIdx.x * 256 + threadIdx.x;   // 4096 total
    if (idx >= 4096) return;
    int li = idx >> 11, rem = idx & 2047;
    int n = rem >> 7, k = rem & 127;
    WfT[idx] = (n < C_OUT) ? (unsigned short)f2bf(Wf[(li * 128 + k) * C_OUT + n]) : 0;
}

// ---------------- MFMA GEMM + fused BN-prologue + fused readout partial ----------
// hl[M,128](bf16, row-scaled by dinv) = bnrelu(A) @ W ; optionally
// out[M,10] (=|+=) bnrelu(A) @ WfT-slice (+ bias). mode: 0=none, 1=write+bias, 2=accum.

__global__ __launch_bounds__(256) void k_gemm(const float* __restrict__ A,
                                              const unsigned short* __restrict__ WT,
                                              unsigned short* __restrict__ hl,
                                              const float* __restrict__ sums,
                                              const float* __restrict__ g,
                                              const float* __restrict__ be,
                                              const float* __restrict__ dinvp,
                                              const unsigned short* __restrict__ WfT,
                                              const float* __restrict__ bfv,
                                              float* __restrict__ outp, int mode) {
    __shared__ unsigned short As[128 * 128];  // 32 KB
    __shared__ unsigned short Ws[128 * 128];  // 32 KB
    int tid = threadIdx.x;
    int row0 = blockIdx.x * 128;

    // per-thread BN scale/shift: this thread only stages columns cc..cc+3
    int cc = (tid & 31) * 4;
    float4 s4 = make_float4(1.f, 1.f, 1.f, 1.f);
    float4 t4 = make_float4(0.f, 0.f, 0.f, 0.f);
    if (sums) {
        float4 sm_ = *(const float4*)&sums[cc];
        float4 sq_ = *(const float4*)&sums[128 + cc];
        float4 gg = *(const float4*)&g[cc];
        float4 bb = *(const float4*)&be[cc];
        float m0 = sm_.x * (1.0f / N_NODES), m1 = sm_.y * (1.0f / N_NODES);
        float m2 = sm_.z * (1.0f / N_NODES), m3 = sm_.w * (1.0f / N_NODES);
        s4.x = gg.x * rsqrtf(fmaxf(sq_.x * (1.0f / N_NODES) - m0 * m0, 0.f) + BN_EPS);
        s4.y = gg.y * rsqrtf(fmaxf(sq_.y * (1.0f / N_NODES) - m1 * m1, 0.f) + BN_EPS);
        s4.z = gg.z * rsqrtf(fmaxf(sq_.z * (1.0f / N_NODES) - m2 * m2, 0.f) + BN_EPS);
        s4.w = gg.w * rsqrtf(fmaxf(sq_.w * (1.0f / N_NODES) - m3 * m3, 0.f) + BN_EPS);
        t4.x = bb.x - m0 * s4.x;  t4.y = bb.y - m1 * s4.y;
        t4.z = bb.z - m2 * s4.z;  t4.w = bb.w - m3 * s4.w;
    }

    // stage Ws (bf16 W^T [n][k]); XOR swizzle in 16B blocks: 2-way conflicts max (free)
    const ushort4* WT4 = (const ushort4*)WT;
#pragma unroll
    for (int i = 0; i < 16; ++i) {
        int idx = i * 256 + tid;
        int r = idx >> 5, c4 = idx & 31;
        ushort4 v = WT4[idx];
        int swz = (c4 >> 1) ^ (r & 15);
        *(ushort4*)&Ws[r * 128 + swz * 8 + (c4 & 1) * 4] = v;
    }
    // stage As: fp32 read, optional BN+ReLU, cvt bf16, swizzled write
    const float4* A4 = (const float4*)A;
#pragma unroll
    for (int i = 0; i < 16; ++i) {
        int idx = i * 256 + tid;
        int r = idx >> 5, c4 = idx & 31;
        int gr = row0 + r;
        float4 v = make_float4(0.f, 0.f, 0.f, 0.f);
        if (gr < N_NODES) v = A4[(size_t)gr * 32 + c4];
        if (sums) {
            v.x = fmaxf(v.x * s4.x + t4.x, 0.f);
            v.y = fmaxf(v.y * s4.y + t4.y, 0.f);
            v.z = fmaxf(v.z * s4.z + t4.z, 0.f);
            v.w = fmaxf(v.w * s4.w + t4.w, 0.f);
        }
        ushort4 o;
        o.x = (unsigned short)f2bf(v.x);
        o.y = (unsigned short)f2bf(v.y);
        o.z = (unsigned short)f2bf(v.z);
        o.w = (unsigned short)f2bf(v.w);
        int swz = (c4 >> 1) ^ (r & 15);
        *(ushort4*)&As[r * 128 + swz * 8 + (c4 & 1) * 4] = o;
    }
    __syncthreads();

    int wave = tid >> 6, lane = tid & 63;
    int quad = lane >> 4, l16 = lane & 15;
    int m0 = wave * 32;

    // a-frags: A[m=lane&15][k = ks*32 + quad*8 + j]
    bf16x8 af[2][4];
#pragma unroll
    for (int mt = 0; mt < 2; ++mt) {
        int m = m0 + mt * 16 + l16;
#pragma unroll
        for (int ks = 0; ks < 4; ++ks) {
            int swz = (ks * 4 + quad) ^ (m & 15);
            af[mt][ks] = *(bf16x8*)&As[m * 128 + swz * 8];
        }
    }

    f32x4 acc[8][2];
#pragma unroll
    for (int nt = 0; nt < 8; ++nt)
#pragma unroll
        for (int mt = 0; mt < 2; ++mt) acc[nt][mt] = (f32x4){0.f, 0.f, 0.f, 0.f};

#pragma unroll
    for (int nt = 0; nt < 8; ++nt) {
        int n = nt * 16 + l16;
        bf16x8 bfr[4];
#pragma unroll
        for (int ks = 0; ks < 4; ++ks) {
            int swz = (ks * 4 + quad) ^ (n & 15);
            bfr[ks] = *(bf16x8*)&Ws[n * 128 + swz * 8];
        }
#pragma unroll
        for (int mt = 0; mt < 2; ++mt)
#pragma unroll
            for (int ks = 0; ks < 4; ++ks)
                acc[nt][mt] = __builtin_amdgcn_mfma_f32_16x16x32_bf16(
                    af[mt][ks], bfr[ks], acc[nt][mt], 0, 0, 0);
    }

    // fused readout partial: out (=|+=) h_staged @ WfT (+bias). 8 extra MFMAs.
    if (mode != 0) {
        f32x4 accO[2] = {(f32x4){0.f, 0.f, 0.f, 0.f}, (f32x4){0.f, 0.f, 0.f, 0.f}};
#pragma unroll
        for (int ks = 0; ks < 4; ++ks) {
            int chunk = ks * 4 + quad;
            bf16x8 bw = *(const bf16x8*)&WfT[l16 * 128 + chunk * 8];  // tiny, L2-hot
            accO[0] = __builtin_amdgcn_mfma_f32_16x16x32_bf16(af[0][ks], bw, accO[0], 0, 0, 0);
            accO[1] = __builtin_amdgcn_mfma_f32_16x16x32_bf16(af[1][ks], bw, accO[1], 0, 0, 0);
        }
        if (l16 < C_OUT) {
#pragma unroll
            for (int mt = 0; mt < 2; ++mt)
#pragma unroll
                for (int reg = 0; reg < 4; ++reg) {
                    int m = row0 + m0 + mt * 16 + quad * 4 + reg;
                    if (m < N_NODES) {
                        size_t o = (size_t)m * C_OUT + l16;
                        float v = accO[mt][reg];
                        if (mode == 1) outp[o] = v + bfv[l16];
                        else outp[o] += v;
                    }
                }
        }
    }

    // C/D: col = lane&15, row = quad*4 + reg; scale by dinv, store bf16
#pragma unroll
    for (int mt = 0; mt < 2; ++mt) {
#pragma unroll
        for (int reg = 0; reg < 4; ++reg) {
            int m = row0 + m0 + mt * 16 + quad * 4 + reg;
            if (m < N_NODES) {
                float di = dinvp[m];
#pragma unroll
                for (int nt = 0; nt < 8; ++nt) {
                    int n = nt * 16 + l16;
                    hl[(size_t)m * 128 + n] = (unsigned short)f2bf(acc[nt][mt][reg] * di);
                }
            }
        }
    }
}

// ---------------- Aggregation: one wave per node, 2 bf16/lane, no barriers ----------------
// R6 lesson: fusing BN stats here (1024-thr blocks + __syncthreads + 6x atomics)
// tripled the time via straggler coupling. Keep waves independent.

__global__ void k_agg(const unsigned short* __restrict__ hl, const int* __restrict__ csr_src,
                      const int* __restrict__ offsets, const float* __restrict__ dinv,
                      float* __restrict__ agg) {
    int node = (int)((blockIdx.x * blockDim.x + threadIdx.x) >> 6);
    int lane = threadIdx.x & 63;
    if (node >= N_NODES) return;
    int beg = offsets[node], end = offsets[node + 1];
    float ax = 0.f, ay = 0.f;
    int e = beg;
    for (; e + 1 < end; e += 2) {
        int j0 = csr_src[e];
        int j1 = csr_src[e + 1];
        uint32 p0 = *(const uint32*)&hl[(size_t)j0 * 128 + lane * 2];
        uint32 p1 = *(const uint32*)&hl[(size_t)j1 * 128 + lane * 2];
        ax += bf2f(p0 & 0xFFFFu) + bf2f(p1 & 0xFFFFu);
        ay += bf2f(p0 >> 16) + bf2f(p1 >> 16);
    }
    if (e < end) {
        int j = csr_src[e];
        uint32 p = *(const uint32*)&hl[(size_t)j * 128 + lane * 2];
        ax += bf2f(p & 0xFFFFu);
        ay += bf2f(p >> 16);
    }
    float di = dinv[node];
    *(float2*)&agg[(size_t)node * 128 + lane * 2] = make_float2(ax * di, ay * di);
}

// ---------------- BN stats (standalone; 512 blocks, 131K atomics total) ----------------

__global__ void k_bn_stats(const float* __restrict__ agg, float* __restrict__ sums) {
    __shared__ float sm[256];
    int tid = threadIdx.x;
    int c = tid & 127;
    float s = 0.f, q = 0.f;
    for (int r = blockIdx.x * 2 + (tid >> 7); r < N_NODES; r += gridDim.x * 2) {
        float v = agg[(size_t)r * 128 + c];
        s += v;
        q += v * v;
    }
    sm[tid] = s;
    __syncthreads();
    if (tid < 128) atomicAdd(&sums[c], sm[tid] + sm[tid + 128]);
    __syncthreads();
    sm[tid] = q;
    __syncthreads();
    if (tid < 128) atomicAdd(&sums[128 + c], sm[tid] + sm[tid + 128]);
}

// ---------------- Final readout (layer 3 only): out += bnrelu(h) @ Wf[256:384,:] ----

__global__ void k_out(const float* __restrict__ h, const float* __restrict__ Wf,
                      float* __restrict__ out, int base,
                      const float* __restrict__ sums,
                      const float* __restrict__ g, const float* __restrict__ be) {
    __shared__ float Wl[128 * C_OUT];
    __shared__ float scl[128], shl[128];
    int tid = threadIdx.x;
    for (int i = tid; i < 128 * C_OUT; i += 256) Wl[i] = Wf[base * C_OUT + i];
    if (tid < 128) {
        float mean = sums[tid] * (1.0f / N_NODES);
        float var = fmaxf(sums[128 + tid] * (1.0f / N_NODES) - mean * mean, 0.f);
        float s = g[tid] * rsqrtf(var + BN_EPS);
        scl[tid] = s;
        shl[tid] = be[tid] - mean * s;
    }
    __syncthreads();
    int node = blockIdx.x * 4 + (tid >> 6);
    if (node >= N_NODES) return;
    int lane = tid & 63;
    float acc[C_OUT];
#pragma unroll
    for (int o = 0; o < C_OUT; ++o) acc[o] = 0.f;
#pragma unroll
    for (int t = 0; t < 128; t += 64) {
        int c = t + lane;
        float v = h[(size_t)node * 128 + c];
        v = fmaxf(v * scl[c] + shl[c], 0.f);
#pragma unroll
        for (int o = 0; o < C_OUT; ++o) acc[o] += v * Wl[c * C_OUT + o];
    }
#pragma unroll
    for (int s = 32; s > 0; s >>= 1) {
#pragma unroll
        for (int o = 0; o < C_OUT; ++o) acc[o] += __shfl_down(acc[o], s, 64);
    }
    if (lane == 0) {
#pragma unroll
        for (int o = 0; o < C_OUT; ++o)
            out[(size_t)node * C_OUT + o] += acc[o];
    }
}

// ---------------- launch ----------------

extern "C" void kernel_launch(void* const* d_in, const int* in_sizes, int n_in,
                              void* d_out, int out_size, void* d_ws, size_t ws_size,
                              hipStream_t stream) {
    const float* x  = (const float*)d_in[0];
    const int*   ei = (const int*)d_in[1];
    const float* W1 = (const float*)d_in[2];
    const float* W2 = (const float*)d_in[4];
    const float* W3 = (const float*)d_in[6];
    // b1/b2/b3 absorbed exactly by BN mean-subtraction
    const float* g1  = (const float*)d_in[8];
    const float* be1 = (const float*)d_in[9];
    const float* g2  = (const float*)d_in[10];
    const float* be2 = (const float*)d_in[11];
    const float* g3  = (const float*)d_in[12];
    const float* be3 = (const float*)d_in[13];
    const float* Wf  = (const float*)d_in[14];
    const float* bf  = (const float*)d_in[15];
    float* out = (float*)d_out;

    char* ws = (char*)d_ws;
    size_t off = 0;
    auto alloc = [&](size_t bytes) -> void* {
        void* p = ws + off;
        off = (off + bytes + 255) & ~(size_t)255;
        return p;
    };
    int*   deg      = (int*)alloc((size_t)N_NODES * 4);
    int*   head     = (int*)alloc((size_t)N_NODES * 4);
    int*   next     = (int*)alloc((size_t)N_EDGES * 4);
    int*   offsets  = (int*)alloc((size_t)(N_NODES + 1) * 4);
    int*   blocksum = (int*)alloc((size_t)SCAN_BLOCKS * 4);
    int*   csr_src  = (int*)alloc((size_t)(N_EDGES + N_NODES) * 4);
    float* dinv     = (float*)alloc((size_t)N_NODES * 4);
    float* sums     = (float*)alloc(768 * 4);
    unsigned short* WT  = (unsigned short*)alloc((size_t)3 * 128 * 128 * 2);
    unsigned short* WfT = (unsigned short*)alloc((size_t)2 * 16 * 128 * 2);
    unsigned short* hl  = (unsigned short*)alloc((size_t)N_NODES * 128 * 2);
    float* bufA    = (float*)alloc((size_t)N_NODES * 128 * 4);
    float* bufB    = (float*)alloc((size_t)N_NODES * 128 * 4);

    const int TPB = 256;
    k_prep<<<384, 128, 0, stream>>>(W1, W2, W3, WT);
    k_prepf<<<16, 256, 0, stream>>>(Wf, WfT);
    k_init<<<(N_NODES + TPB - 1) / TPB, TPB, 0, stream>>>(deg, head, sums);
    k_link<<<(N_EDGES + TPB - 1) / TPB, TPB, 0, stream>>>(ei, deg, head, next);
    k_scan1<<<SCAN_BLOCKS, 256, 0, stream>>>(deg, offsets, blocksum, dinv);
    k_scan2<<<1, 256, 0, stream>>>(blocksum, offsets);
    k_scan3<<<SCAN_BLOCKS, 256, 0, stream>>>(offsets, blocksum);
    k_c2csr<<<SCAN_BLOCKS, 256, 0, stream>>>(ei, head, next, offsets, csr_src);

    const int gemm_grid = (N_NODES + 127) / 128;        // 391
    const int agg_grid  = (N_NODES + 3) / 4;            // wave per node, 4/block
    const int out_grid  = (N_NODES + 3) / 4;

    // ---- layer 1 ----
    k_gemm<<<gemm_grid, 256, 0, stream>>>(x, WT, hl, nullptr, nullptr, nullptr, dinv,
                                          nullptr, nullptr, nullptr, 0);
    k_agg<<<agg_grid, 256, 0, stream>>>(hl, csr_src, offsets, dinv, bufA);
    k_bn_stats<<<512, 256, 0, stream>>>(bufA, sums + 0);

    // ---- layer 2 (gemm also emits out = h1 @ Wf0 + bf) ----
    k_gemm<<<gemm_grid, 256, 0, stream>>>(bufA, WT + 16384, hl, sums + 0, g1, be1, dinv,
                                          WfT, bf, out, 1);
    k_agg<<<agg_grid, 256, 0, stream>>>(hl, csr_src, offsets, dinv, bufB);
    k_bn_stats<<<512, 256, 0, stream>>>(bufB, sums + 256);

    // ---- layer 3 (gemm also emits out += h2 @ Wf1) ----
    k_gemm<<<gemm_grid, 256, 0, stream>>>(bufB, WT + 32768, hl, sums + 256, g2, be2, dinv,
                                          WfT + 2048, nullptr, out, 2);
    k_agg<<<agg_grid, 256, 0, stream>>>(hl, csr_src, offsets, dinv, bufA);
    k_bn_stats<<<512, 256, 0, stream>>>(bufA, sums + 512);

    // ---- layer 3 readout (fp32) ----
    k_out<<<out_grid, 256, 0, stream>>>(bufA, Wf, out, 256, sums + 512, g3, be3);
}

// Round 8
// 442.359 us; speedup vs baseline: 1.7780x; 1.1869x over previous
//
#include <hip/hip_runtime.h>

#define N_NODES 50000
#define N_EDGES 800000
#define D 128
#define C_OUT 10
#define BN_EPS 1e-5f
#define CAP 64            // padded adjacency row capacity; P(deg>=63)~1e-17 (Poisson 16)

typedef unsigned int uint32;
typedef __attribute__((ext_vector_type(8))) short bf16x8;
typedef __attribute__((ext_vector_type(4))) float f32x4;

__device__ __forceinline__ float bf2f(unsigned int u16) {
    unsigned int x = u16 << 16;
    float f;
    __builtin_memcpy(&f, &x, 4);
    return f;
}
__device__ __forceinline__ unsigned int f2bf(float f) {
    unsigned int x;
    __builtin_memcpy(&x, &f, 4);
    unsigned int r = x + 0x7FFFu + ((x >> 16) & 1u);  // RNE
    return r >> 16;
}

// ---------------- adjacency: 1-atomic linked-list build, one walk -> padded rows ----
// R3: random 4B scatter = 54MB line writeback. R7: k_link with 2 atomics/edge = 80us
// (atomic-serialization bound). Here: 1 atomicExch/edge; deg recovered as chain
// length in k_walk; padded rows (256B-aligned) make walk writes ~2 lines/node.

__global__ void k_init(int* head, float* sums) {
    int i = blockIdx.x * blockDim.x + threadIdx.x;
    if (i < N_NODES) head[i] = -1;
    if (i < 768) sums[i] = 0.0f;          // 3 layers x (sum|sumsq)
}

__global__ void k_link(const int* __restrict__ ei, int* __restrict__ head,
                       int* __restrict__ next) {
    int e = blockIdx.x * blockDim.x + threadIdx.x;
    if (e >= N_EDGES) return;
    int d = ei[N_EDGES + e];                    // destination (col)
    next[e] = atomicExch(&head[d], e);          // only atomic in the build
}

__global__ void k_walk(const int* __restrict__ ei, const int* __restrict__ head,
                       const int* __restrict__ next, int* __restrict__ adj,
                       int* __restrict__ cnt, float* __restrict__ dinv) {
    int i = blockIdx.x * blockDim.x + threadIdx.x;
    if (i >= N_NODES) return;
    int* row = adj + ((size_t)i << 6);
    row[0] = i;                                 // self loop first
    int j = 1;
    int e = head[i];
    while (e >= 0 && j < CAP) {
        row[j++] = ei[e];                       // source id
        e = next[e];
    }
    cnt[i] = j;
    dinv[i] = rsqrtf((float)j);                 // deg = chain length + self
}

// ---------------- W prep: fp32 [k][n] -> bf16 transposed [n][k] ----------------

__global__ void k_prep(const float* __restrict__ W1, const float* __restrict__ W2,
                       const float* __restrict__ W3, unsigned short* __restrict__ WT) {
    int mat = blockIdx.x >> 7;
    int n = blockIdx.x & 127;
    int k = threadIdx.x;  // 128 threads
    const float* W = (mat == 0) ? W1 : ((mat == 1) ? W2 : W3);
    WT[mat * 16384 + n * 128 + k] = (unsigned short)f2bf(W[k * 128 + n]);
}

// Wf slices 0,1 (for fused readout in gemm2/gemm3): bf16 [li][n(16, pad0)][k(128)]
__global__ void k_prepf(const float* __restrict__ Wf, unsigned short* __restrict__ WfT) {
    int idx = blockIdx.x * 256 + threadIdx.x;   // 4096 total
    if (idx >= 4096) return;
    int li = idx >> 11, rem = idx & 2047;
    int n = rem >> 7, k = rem & 127;
    WfT[idx] = (n < C_OUT) ? (unsigned short)f2bf(Wf[(li * 128 + k) * C_OUT + n]) : 0;
}

// ---------------- MFMA GEMM + fused BN-prologue + fused readout partial ----------
// hl[M,128](bf16, row-scaled by dinv) = bnrelu(A) @ W ; optionally
// out[M,10] (=|+=) bnrelu(A) @ WfT-slice (+ bias). mode: 0=none, 1=write+bias, 2=accum.

__global__ __launch_bounds__(256) void k_gemm(const float* __restrict__ A,
                                              const unsigned short* __restrict__ WT,
                                              unsigned short* __restrict__ hl,
                                              const float* __restrict__ sums,
                                              const float* __restrict__ g,
                                              const float* __restrict__ be,
                                              const float* __restrict__ dinvp,
                                              const unsigned short* __restrict__ WfT,
                                              const float* __restrict__ bfv,
                                              float* __restrict__ outp, int mode) {
    __shared__ unsigned short As[128 * 128];  // 32 KB
    __shared__ unsigned short Ws[128 * 128];  // 32 KB
    int tid = threadIdx.x;
    int row0 = blockIdx.x * 128;

    // per-thread BN scale/shift: this thread only stages columns cc..cc+3
    int cc = (tid & 31) * 4;
    float4 s4 = make_float4(1.f, 1.f, 1.f, 1.f);
    float4 t4 = make_float4(0.f, 0.f, 0.f, 0.f);
    if (sums) {
        float4 sm_ = *(const float4*)&sums[cc];
        float4 sq_ = *(const float4*)&sums[128 + cc];
        float4 gg = *(const float4*)&g[cc];
        float4 bb = *(const float4*)&be[cc];
        float m0 = sm_.x * (1.0f / N_NODES), m1 = sm_.y * (1.0f / N_NODES);
        float m2 = sm_.z * (1.0f / N_NODES), m3 = sm_.w * (1.0f / N_NODES);
        s4.x = gg.x * rsqrtf(fmaxf(sq_.x * (1.0f / N_NODES) - m0 * m0, 0.f) + BN_EPS);
        s4.y = gg.y * rsqrtf(fmaxf(sq_.y * (1.0f / N_NODES) - m1 * m1, 0.f) + BN_EPS);
        s4.z = gg.z * rsqrtf(fmaxf(sq_.z * (1.0f / N_NODES) - m2 * m2, 0.f) + BN_EPS);
        s4.w = gg.w * rsqrtf(fmaxf(sq_.w * (1.0f / N_NODES) - m3 * m3, 0.f) + BN_EPS);
        t4.x = bb.x - m0 * s4.x;  t4.y = bb.y - m1 * s4.y;
        t4.z = bb.z - m2 * s4.z;  t4.w = bb.w - m3 * s4.w;
    }

    // stage Ws (bf16 W^T [n][k]); XOR swizzle in 16B blocks: 2-way conflicts max (free)
    const ushort4* WT4 = (const ushort4*)WT;
#pragma unroll
    for (int i = 0; i < 16; ++i) {
        int idx = i * 256 + tid;
        int r = idx >> 5, c4 = idx & 31;
        ushort4 v = WT4[idx];
        int swz = (c4 >> 1) ^ (r & 15);
        *(ushort4*)&Ws[r * 128 + swz * 8 + (c4 & 1) * 4] = v;
    }
    // stage As: fp32 read, optional BN+ReLU, cvt bf16, swizzled write
    const float4* A4 = (const float4*)A;
#pragma unroll
    for (int i = 0; i < 16; ++i) {
        int idx = i * 256 + tid;
        int r = idx >> 5, c4 = idx & 31;
        int gr = row0 + r;
        float4 v = make_float4(0.f, 0.f, 0.f, 0.f);
        if (gr < N_NODES) v = A4[(size_t)gr * 32 + c4];
        if (sums) {
            v.x = fmaxf(v.x * s4.x + t4.x, 0.f);
            v.y = fmaxf(v.y * s4.y + t4.y, 0.f);
            v.z = fmaxf(v.z * s4.z + t4.z, 0.f);
            v.w = fmaxf(v.w * s4.w + t4.w, 0.f);
        }
        ushort4 o;
        o.x = (unsigned short)f2bf(v.x);
        o.y = (unsigned short)f2bf(v.y);
        o.z = (unsigned short)f2bf(v.z);
        o.w = (unsigned short)f2bf(v.w);
        int swz = (c4 >> 1) ^ (r & 15);
        *(ushort4*)&As[r * 128 + swz * 8 + (c4 & 1) * 4] = o;
    }
    __syncthreads();

    int wave = tid >> 6, lane = tid & 63;
    int quad = lane >> 4, l16 = lane & 15;
    int m0 = wave * 32;

    // a-frags: A[m=lane&15][k = ks*32 + quad*8 + j]
    bf16x8 af[2][4];
#pragma unroll
    for (int mt = 0; mt < 2; ++mt) {
        int m = m0 + mt * 16 + l16;
#pragma unroll
        for (int ks = 0; ks < 4; ++ks) {
            int swz = (ks * 4 + quad) ^ (m & 15);
            af[mt][ks] = *(bf16x8*)&As[m * 128 + swz * 8];
        }
    }

    f32x4 acc[8][2];
#pragma unroll
    for (int nt = 0; nt < 8; ++nt)
#pragma unroll
        for (int mt = 0; mt < 2; ++mt) acc[nt][mt] = (f32x4){0.f, 0.f, 0.f, 0.f};

#pragma unroll
    for (int nt = 0; nt < 8; ++nt) {
        int n = nt * 16 + l16;
        bf16x8 bfr[4];
#pragma unroll
        for (int ks = 0; ks < 4; ++ks) {
            int swz = (ks * 4 + quad) ^ (n & 15);
            bfr[ks] = *(bf16x8*)&Ws[n * 128 + swz * 8];
        }
#pragma unroll
        for (int mt = 0; mt < 2; ++mt)
#pragma unroll
            for (int ks = 0; ks < 4; ++ks)
                acc[nt][mt] = __builtin_amdgcn_mfma_f32_16x16x32_bf16(
                    af[mt][ks], bfr[ks], acc[nt][mt], 0, 0, 0);
    }

    // fused readout partial: out (=|+=) h_staged @ WfT (+bias). 8 extra MFMAs.
    if (mode != 0) {
        f32x4 accO[2] = {(f32x4){0.f, 0.f, 0.f, 0.f}, (f32x4){0.f, 0.f, 0.f, 0.f}};
#pragma unroll
        for (int ks = 0; ks < 4; ++ks) {
            int chunk = ks * 4 + quad;
            bf16x8 bw = *(const bf16x8*)&WfT[l16 * 128 + chunk * 8];  // tiny, L2-hot
            accO[0] = __builtin_amdgcn_mfma_f32_16x16x32_bf16(af[0][ks], bw, accO[0], 0, 0, 0);
            accO[1] = __builtin_amdgcn_mfma_f32_16x16x32_bf16(af[1][ks], bw, accO[1], 0, 0, 0);
        }
        if (l16 < C_OUT) {
#pragma unroll
            for (int mt = 0; mt < 2; ++mt)
#pragma unroll
                for (int reg = 0; reg < 4; ++reg) {
                    int m = row0 + m0 + mt * 16 + quad * 4 + reg;
                    if (m < N_NODES) {
                        size_t o = (size_t)m * C_OUT + l16;
                        float v = accO[mt][reg];
                        if (mode == 1) outp[o] = v + bfv[l16];
                        else outp[o] += v;
                    }
                }
        }
    }

    // C/D: col = lane&15, row = quad*4 + reg; scale by dinv, store bf16
#pragma unroll
    for (int mt = 0; mt < 2; ++mt) {
#pragma unroll
        for (int reg = 0; reg < 4; ++reg) {
            int m = row0 + m0 + mt * 16 + quad * 4 + reg;
            if (m < N_NODES) {
                float di = dinvp[m];
#pragma unroll
                for (int nt = 0; nt < 8; ++nt) {
                    int n = nt * 16 + l16;
                    hl[(size_t)m * 128 + n] = (unsigned short)f2bf(acc[nt][mt][reg] * di);
                }
            }
        }
    }
}

// ---------------- Aggregation: one wave per node, padded adj rows, no barriers ----------

__global__ void k_agg(const unsigned short* __restrict__ hl, const int* __restrict__ adj,
                      const int* __restrict__ cnt, const float* __restrict__ dinv,
                      float* __restrict__ agg) {
    int node = (int)((blockIdx.x * blockDim.x + threadIdx.x) >> 6);
    int lane = threadIdx.x & 63;
    if (node >= N_NODES) return;
    const int* row = adj + ((size_t)node << 6);   // wave-uniform scalar reads
    int n = cnt[node];
    float ax = 0.f, ay = 0.f;
    int e = 0;
    for (; e + 3 < n; e += 4) {
        int j0 = row[e], j1 = row[e + 1], j2 = row[e + 2], j3 = row[e + 3];
        uint32 p0 = *(const uint32*)&hl[(size_t)j0 * 128 + lane * 2];
        uint32 p1 = *(const uint32*)&hl[(size_t)j1 * 128 + lane * 2];
        uint32 p2 = *(const uint32*)&hl[(size_t)j2 * 128 + lane * 2];
        uint32 p3 = *(const uint32*)&hl[(size_t)j3 * 128 + lane * 2];
        ax += bf2f(p0 & 0xFFFFu) + bf2f(p1 & 0xFFFFu) +
              bf2f(p2 & 0xFFFFu) + bf2f(p3 & 0xFFFFu);
        ay += bf2f(p0 >> 16) + bf2f(p1 >> 16) + bf2f(p2 >> 16) + bf2f(p3 >> 16);
    }
    for (; e < n; ++e) {
        int j = row[e];
        uint32 p = *(const uint32*)&hl[(size_t)j * 128 + lane * 2];
        ax += bf2f(p & 0xFFFFu);
        ay += bf2f(p >> 16);
    }
    float di = dinv[node];
    *(float2*)&agg[(size_t)node * 128 + lane * 2] = make_float2(ax * di, ay * di);
}

// ---------------- BN stats (standalone; 512 blocks, 131K atomics total) ----------------

__global__ void k_bn_stats(const float* __restrict__ agg, float* __restrict__ sums) {
    __shared__ float sm[256];
    int tid = threadIdx.x;
    int c = tid & 127;
    float s = 0.f, q = 0.f;
    for (int r = blockIdx.x * 2 + (tid >> 7); r < N_NODES; r += gridDim.x * 2) {
        float v = agg[(size_t)r * 128 + c];
        s += v;
        q += v * v;
    }
    sm[tid] = s;
    __syncthreads();
    if (tid < 128) atomicAdd(&sums[c], sm[tid] + sm[tid + 128]);
    __syncthreads();
    sm[tid] = q;
    __syncthreads();
    if (tid < 128) atomicAdd(&sums[128 + c], sm[tid] + sm[tid + 128]);
}

// ---------------- Final readout (layer 3 only): out += bnrelu(h) @ Wf[256:384,:] ----

__global__ void k_out(const float* __restrict__ h, const float* __restrict__ Wf,
                      float* __restrict__ out, int base,
                      const float* __restrict__ sums,
                      const float* __restrict__ g, const float* __restrict__ be) {
    __shared__ float Wl[128 * C_OUT];
    __shared__ float scl[128], shl[128];
    int tid = threadIdx.x;
    for (int i = tid; i < 128 * C_OUT; i += 256) Wl[i] = Wf[base * C_OUT + i];
    if (tid < 128) {
        float mean = sums[tid] * (1.0f / N_NODES);
        float var = fmaxf(sums[128 + tid] * (1.0f / N_NODES) - mean * mean, 0.f);
        float s = g[tid] * rsqrtf(var + BN_EPS);
        scl[tid] = s;
        shl[tid] = be[tid] - mean * s;
    }
    __syncthreads();
    int node = blockIdx.x * 4 + (tid >> 6);
    if (node >= N_NODES) return;
    int lane = tid & 63;
    float acc[C_OUT];
#pragma unroll
    for (int o = 0; o < C_OUT; ++o) acc[o] = 0.f;
#pragma unroll
    for (int t = 0; t < 128; t += 64) {
        int c = t + lane;
        float v = h[(size_t)node * 128 + c];
        v = fmaxf(v * scl[c] + shl[c], 0.f);
#pragma unroll
        for (int o = 0; o < C_OUT; ++o) acc[o] += v * Wl[c * C_OUT + o];
    }
#pragma unroll
    for (int s = 32; s > 0; s >>= 1) {
#pragma unroll
        for (int o = 0; o < C_OUT; ++o) acc[o] += __shfl_down(acc[o], s, 64);
    }
    if (lane == 0) {
#pragma unroll
        for (int o = 0; o < C_OUT; ++o)
            out[(size_t)node * C_OUT + o] += acc[o];
    }
}

// ---------------- launch ----------------

extern "C" void kernel_launch(void* const* d_in, const int* in_sizes, int n_in,
                              void* d_out, int out_size, void* d_ws, size_t ws_size,
                              hipStream_t stream) {
    const float* x  = (const float*)d_in[0];
    const int*   ei = (const int*)d_in[1];
    const float* W1 = (const float*)d_in[2];
    const float* W2 = (const float*)d_in[4];
    const float* W3 = (const float*)d_in[6];
    // b1/b2/b3 absorbed exactly by BN mean-subtraction
    const float* g1  = (const float*)d_in[8];
    const float* be1 = (const float*)d_in[9];
    const float* g2  = (const float*)d_in[10];
    const float* be2 = (const float*)d_in[11];
    const float* g3  = (const float*)d_in[12];
    const float* be3 = (const float*)d_in[13];
    const float* Wf  = (const float*)d_in[14];
    const float* bf  = (const float*)d_in[15];
    float* out = (float*)d_out;

    char* ws = (char*)d_ws;
    size_t off = 0;
    auto alloc = [&](size_t bytes) -> void* {
        void* p = ws + off;
        off = (off + bytes + 255) & ~(size_t)255;
        return p;
    };
    int*   head  = (int*)alloc((size_t)N_NODES * 4);
    int*   next  = (int*)alloc((size_t)N_EDGES * 4);
    int*   adj   = (int*)alloc((size_t)N_NODES * CAP * 4);   // 12.8 MB padded rows
    int*   cnt   = (int*)alloc((size_t)N_NODES * 4);
    float* dinv  = (float*)alloc((size_t)N_NODES * 4);
    float* sums  = (float*)alloc(768 * 4);
    unsigned short* WT  = (unsigned short*)alloc((size_t)3 * 128 * 128 * 2);
    unsigned short* WfT = (unsigned short*)alloc((size_t)2 * 16 * 128 * 2);
    unsigned short* hl  = (unsigned short*)alloc((size_t)N_NODES * 128 * 2);  // bf16
    float* bufA  = (float*)alloc((size_t)N_NODES * 128 * 4);
    float* bufB  = (float*)alloc((size_t)N_NODES * 128 * 4);

    const int TPB = 256;
    k_prep<<<384, 128, 0, stream>>>(W1, W2, W3, WT);
    k_prepf<<<16, 256, 0, stream>>>(Wf, WfT);
    k_init<<<(N_NODES + TPB - 1) / TPB, TPB, 0, stream>>>(head, sums);
    k_link<<<(N_EDGES + TPB - 1) / TPB, TPB, 0, stream>>>(ei, head, next);
    k_walk<<<(N_NODES + TPB - 1) / TPB, TPB, 0, stream>>>(ei, head, next, adj, cnt, dinv);

    const int gemm_grid = (N_NODES + 127) / 128;        // 391
    const int agg_grid  = (N_NODES + 3) / 4;            // wave per node, 4/block
    const int out_grid  = (N_NODES + 3) / 4;

    // ---- layer 1 ----
    k_gemm<<<gemm_grid, 256, 0, stream>>>(x, WT, hl, nullptr, nullptr, nullptr, dinv,
                                          nullptr, nullptr, nullptr, 0);
    k_agg<<<agg_grid, 256, 0, stream>>>(hl, adj, cnt, dinv, bufA);
    k_bn_stats<<<512, 256, 0, stream>>>(bufA, sums + 0);

    // ---- layer 2 (gemm also emits out = h1 @ Wf0 + bf) ----
    k_gemm<<<gemm_grid, 256, 0, stream>>>(bufA, WT + 16384, hl, sums + 0, g1, be1, dinv,
                                          WfT, bf, out, 1);
    k_agg<<<agg_grid, 256, 0, stream>>>(hl, adj, cnt, dinv, bufB);
    k_bn_stats<<<512, 256, 0, stream>>>(bufB, sums + 256);

    // ---- layer 3 (gemm also emits out += h2 @ Wf1) ----
    k_gemm<<<gemm_grid, 256, 0, stream>>>(bufB, WT + 32768, hl, sums + 256, g2, be2, dinv,
                                          WfT + 2048, nullptr, out, 2);
    k_agg<<<agg_grid, 256, 0, stream>>>(hl, adj, cnt, dinv, bufA);
    k_bn_stats<<<512, 256, 0, stream>>>(bufA, sums + 512);

    // ---- layer 3 readout (fp32) ----
    k_out<<<out_grid, 256, 0, stream>>>(bufA, Wf, out, 256, sums + 512, g3, be3);
}

// Round 9
// 426.032 us; speedup vs baseline: 1.8461x; 1.0383x over previous
//
#include <hip/hip_runtime.h>

#define N_NODES 50000
#define N_EDGES 800000
#define D 128
#define C_OUT 10
#define BN_EPS 1e-5f
#define CAP 64            // padded adjacency row capacity; P(deg>=63)~1e-17 (Poisson 16)

typedef unsigned int uint32;
typedef __attribute__((ext_vector_type(8))) short bf16x8;
typedef __attribute__((ext_vector_type(4))) float f32x4;

__device__ __forceinline__ float bf2f(unsigned int u16) {
    unsigned int x = u16 << 16;
    float f;
    __builtin_memcpy(&f, &x, 4);
    return f;
}
__device__ __forceinline__ unsigned int f2bf(float f) {
    unsigned int x;
    __builtin_memcpy(&x, &f, 4);
    unsigned int r = x + 0x7FFFu + ((x >> 16) & 1u);  // RNE
    return r >> 16;
}
__device__ __forceinline__ uint32 pack_bf2(float a, float b) {
    return f2bf(a) | (f2bf(b) << 16);
}

// ---------------- adjacency: 1-atomic linked-list build, one walk -> padded rows ----

__global__ void k_init(int* head, float* sums) {
    int i = blockIdx.x * blockDim.x + threadIdx.x;
    if (i < N_NODES) head[i] = -1;
    if (i < 768) sums[i] = 0.0f;          // 3 layers x (sum|sumsq)
}

__global__ void k_link(const int* __restrict__ ei, int* __restrict__ head,
                       int* __restrict__ next) {
    int e = blockIdx.x * blockDim.x + threadIdx.x;
    if (e >= N_EDGES) return;
    int d = ei[N_EDGES + e];                    // destination (col)
    next[e] = atomicExch(&head[d], e);          // only atomic in the build
}

__global__ void k_walk(const int* __restrict__ ei, const int* __restrict__ head,
                       const int* __restrict__ next, int* __restrict__ adj,
                       int* __restrict__ cnt, float* __restrict__ dinv) {
    int i = blockIdx.x * blockDim.x + threadIdx.x;
    if (i >= N_NODES) return;
    int* row = adj + ((size_t)i << 6);
    row[0] = i;                                 // self loop first
    int j = 1;
    int e = head[i];
    while (e >= 0 && j < CAP) {
        row[j++] = ei[e];                       // source id
        e = next[e];
    }
    cnt[i] = j;
    dinv[i] = rsqrtf((float)j);                 // deg = chain length + self
}

// ---------------- W prep: fp32 [k][n] -> bf16 transposed [n][k] ----------------

__global__ void k_prep(const float* __restrict__ W1, const float* __restrict__ W2,
                       const float* __restrict__ W3, unsigned short* __restrict__ WT) {
    int mat = blockIdx.x >> 7;
    int n = blockIdx.x & 127;
    int k = threadIdx.x;  // 128 threads
    const float* W = (mat == 0) ? W1 : ((mat == 1) ? W2 : W3);
    WT[mat * 16384 + n * 128 + k] = (unsigned short)f2bf(W[k * 128 + n]);
}

// Wf slices 0,1,2: bf16 [li][n(16, pad0)][k(128)]
__global__ void k_prepf(const float* __restrict__ Wf, unsigned short* __restrict__ WfT) {
    int idx = blockIdx.x * 256 + threadIdx.x;   // 6144 total
    if (idx >= 6144) return;
    int li = idx >> 11, rem = idx & 2047;
    int n = rem >> 7, k = rem & 127;
    WfT[idx] = (n < C_OUT) ? (unsigned short)f2bf(Wf[(li * 128 + k) * C_OUT + n]) : 0;
}

// ---------------- MFMA GEMM + fused BN-prologue + fused readout partial ----------
// hl[M,128](bf16, row-scaled by dinv) = bnrelu(A) @ W.
// A source: Af32 (layer 1, no BN) XOR Abf (bf16 agg output, BN'd). Optionally
// out[M,10] (=|+=) bnrelu(A) @ WfT-slice (+ bias). mode: 0=none, 1=write+bias, 2=accum.

__global__ __launch_bounds__(256) void k_gemm(const float* __restrict__ Af32,
                                              const unsigned short* __restrict__ Abf,
                                              const unsigned short* __restrict__ WT,
                                              unsigned short* __restrict__ hl,
                                              const float* __restrict__ sums,
                                              const float* __restrict__ g,
                                              const float* __restrict__ be,
                                              const float* __restrict__ dinvp,
                                              const unsigned short* __restrict__ WfT,
                                              const float* __restrict__ bfv,
                                              float* __restrict__ outp, int mode) {
    __shared__ unsigned short As[128 * 128];  // 32 KB
    __shared__ unsigned short Ws[128 * 128];  // 32 KB
    int tid = threadIdx.x;
    int row0 = blockIdx.x * 128;

    // stage Ws (bf16 W^T [n][k]); XOR swizzle in 16B blocks: 2-way conflicts max (free)
    const ushort4* WT4 = (const ushort4*)WT;
#pragma unroll
    for (int i = 0; i < 16; ++i) {
        int idx = i * 256 + tid;
        int r = idx >> 5, c4 = idx & 31;
        ushort4 v = WT4[idx];
        int swz = (c4 >> 1) ^ (r & 15);
        *(ushort4*)&Ws[r * 128 + swz * 8 + (c4 & 1) * 4] = v;
    }

    if (Abf) {
        // bf16 A path: thread stages 8 fixed columns cc..cc+7 (c8 = tid&15)
        int c8 = tid & 15, cc = c8 * 8;
        float s8[8], t8[8];
#pragma unroll
        for (int u = 0; u < 8; ++u) {
            float mean = sums[cc + u] * (1.0f / N_NODES);
            float var = fmaxf(sums[128 + cc + u] * (1.0f / N_NODES) - mean * mean, 0.f);
            float s = g[cc + u] * rsqrtf(var + BN_EPS);
            s8[u] = s;
            t8[u] = be[cc + u] - mean * s;
        }
        const uint4* H4 = (const uint4*)Abf;
#pragma unroll
        for (int i = 0; i < 8; ++i) {
            int idx = i * 256 + tid;
            int r = idx >> 4;                   // 0..127
            int gr = row0 + r;
            uint4 v = make_uint4(0, 0, 0, 0);
            if (gr < N_NODES) v = H4[(size_t)gr * 16 + c8];
            uint32 w[4] = {v.x, v.y, v.z, v.w};
            uint32 o[4];
#pragma unroll
            for (int p = 0; p < 4; ++p) {
                float f0 = bf2f(w[p] & 0xFFFFu) * s8[2 * p] + t8[2 * p];
                float f1 = bf2f(w[p] >> 16) * s8[2 * p + 1] + t8[2 * p + 1];
                o[p] = pack_bf2(fmaxf(f0, 0.f), fmaxf(f1, 0.f));
            }
            int swz = c8 ^ (r & 15);
            *(uint4*)&As[r * 128 + swz * 8] = make_uint4(o[0], o[1], o[2], o[3]);
        }
    } else {
        // fp32 A path (layer 1: x, no BN)
        const float4* A4 = (const float4*)Af32;
#pragma unroll
        for (int i = 0; i < 16; ++i) {
            int idx = i * 256 + tid;
            int r = idx >> 5, c4 = idx & 31;
            int gr = row0 + r;
            float4 v = make_float4(0.f, 0.f, 0.f, 0.f);
            if (gr < N_NODES) v = A4[(size_t)gr * 32 + c4];
            ushort4 o;
            o.x = (unsigned short)f2bf(v.x);
            o.y = (unsigned short)f2bf(v.y);
            o.z = (unsigned short)f2bf(v.z);
            o.w = (unsigned short)f2bf(v.w);
            int swz = (c4 >> 1) ^ (r & 15);
            *(ushort4*)&As[r * 128 + swz * 8 + (c4 & 1) * 4] = o;
        }
    }
    __syncthreads();

    int wave = tid >> 6, lane = tid & 63;
    int quad = lane >> 4, l16 = lane & 15;
    int m0 = wave * 32;

    // a-frags: A[m=lane&15][k = ks*32 + quad*8 + j]
    bf16x8 af[2][4];
#pragma unroll
    for (int mt = 0; mt < 2; ++mt) {
        int m = m0 + mt * 16 + l16;
#pragma unroll
        for (int ks = 0; ks < 4; ++ks) {
            int swz = (ks * 4 + quad) ^ (m & 15);
            af[mt][ks] = *(bf16x8*)&As[m * 128 + swz * 8];
        }
    }

    f32x4 acc[8][2];
#pragma unroll
    for (int nt = 0; nt < 8; ++nt)
#pragma unroll
        for (int mt = 0; mt < 2; ++mt) acc[nt][mt] = (f32x4){0.f, 0.f, 0.f, 0.f};

#pragma unroll
    for (int nt = 0; nt < 8; ++nt) {
        int n = nt * 16 + l16;
        bf16x8 bfr[4];
#pragma unroll
        for (int ks = 0; ks < 4; ++ks) {
            int swz = (ks * 4 + quad) ^ (n & 15);
            bfr[ks] = *(bf16x8*)&Ws[n * 128 + swz * 8];
        }
#pragma unroll
        for (int mt = 0; mt < 2; ++mt)
#pragma unroll
            for (int ks = 0; ks < 4; ++ks)
                acc[nt][mt] = __builtin_amdgcn_mfma_f32_16x16x32_bf16(
                    af[mt][ks], bfr[ks], acc[nt][mt], 0, 0, 0);
    }

    // fused readout partial: out (=|+=) staged @ WfT (+bias). 8 extra MFMAs.
    if (mode != 0) {
        f32x4 accO[2] = {(f32x4){0.f, 0.f, 0.f, 0.f}, (f32x4){0.f, 0.f, 0.f, 0.f}};
#pragma unroll
        for (int ks = 0; ks < 4; ++ks) {
            int chunk = ks * 4 + quad;
            bf16x8 bw = *(const bf16x8*)&WfT[l16 * 128 + chunk * 8];  // tiny, L2-hot
            accO[0] = __builtin_amdgcn_mfma_f32_16x16x32_bf16(af[0][ks], bw, accO[0], 0, 0, 0);
            accO[1] = __builtin_amdgcn_mfma_f32_16x16x32_bf16(af[1][ks], bw, accO[1], 0, 0, 0);
        }
        if (l16 < C_OUT) {
#pragma unroll
            for (int mt = 0; mt < 2; ++mt)
#pragma unroll
                for (int reg = 0; reg < 4; ++reg) {
                    int m = row0 + m0 + mt * 16 + quad * 4 + reg;
                    if (m < N_NODES) {
                        size_t o = (size_t)m * C_OUT + l16;
                        float v = accO[mt][reg];
                        if (mode == 1) outp[o] = v + bfv[l16];
                        else outp[o] += v;
                    }
                }
        }
    }

    // C/D: col = lane&15, row = quad*4 + reg; scale by dinv, store bf16
#pragma unroll
    for (int mt = 0; mt < 2; ++mt) {
#pragma unroll
        for (int reg = 0; reg < 4; ++reg) {
            int m = row0 + m0 + mt * 16 + quad * 4 + reg;
            if (m < N_NODES) {
                float di = dinvp[m];
#pragma unroll
                for (int nt = 0; nt < 8; ++nt) {
                    int n = nt * 16 + l16;
                    hl[(size_t)m * 128 + n] = (unsigned short)f2bf(acc[nt][mt][reg] * di);
                }
            }
        }
    }
}

// ---------------- Aggregation: one wave per node, padded adj rows -> bf16 out ----------

__global__ void k_agg(const unsigned short* __restrict__ hl, const int* __restrict__ adj,
                      const int* __restrict__ cnt, const float* __restrict__ dinv,
                      unsigned short* __restrict__ agg) {
    int node = (int)((blockIdx.x * blockDim.x + threadIdx.x) >> 6);
    int lane = threadIdx.x & 63;
    if (node >= N_NODES) return;
    const int* row = adj + ((size_t)node << 6);   // wave-uniform scalar reads
    int n = cnt[node];
    float ax = 0.f, ay = 0.f;
    int e = 0;
    for (; e + 3 < n; e += 4) {
        int j0 = row[e], j1 = row[e + 1], j2 = row[e + 2], j3 = row[e + 3];
        uint32 p0 = *(const uint32*)&hl[(size_t)j0 * 128 + lane * 2];
        uint32 p1 = *(const uint32*)&hl[(size_t)j1 * 128 + lane * 2];
        uint32 p2 = *(const uint32*)&hl[(size_t)j2 * 128 + lane * 2];
        uint32 p3 = *(const uint32*)&hl[(size_t)j3 * 128 + lane * 2];
        ax += bf2f(p0 & 0xFFFFu) + bf2f(p1 & 0xFFFFu) +
              bf2f(p2 & 0xFFFFu) + bf2f(p3 & 0xFFFFu);
        ay += bf2f(p0 >> 16) + bf2f(p1 >> 16) + bf2f(p2 >> 16) + bf2f(p3 >> 16);
    }
    for (; e < n; ++e) {
        int j = row[e];
        uint32 p = *(const uint32*)&hl[(size_t)j * 128 + lane * 2];
        ax += bf2f(p & 0xFFFFu);
        ay += bf2f(p >> 16);
    }
    float di = dinv[node];
    *(uint32*)&agg[(size_t)node * 128 + lane * 2] = pack_bf2(ax * di, ay * di);
}

// ---------------- BN stats over bf16 agg (uint32/lane, 4-wave LDS reduce) ----------------

__global__ __launch_bounds__(256) void k_bn_stats(const unsigned short* __restrict__ agg,
                                                  float* __restrict__ sums) {
    __shared__ float red[4][256];
    int tid = threadIdx.x;
    int lane = tid & 63, w = tid >> 6;
    float sx = 0.f, qx = 0.f, sy = 0.f, qy = 0.f;
    for (int r = blockIdx.x * 4 + w; r < N_NODES; r += gridDim.x * 4) {
        uint32 p = *(const uint32*)&agg[(size_t)r * 128 + lane * 2];
        float x = bf2f(p & 0xFFFFu), y = bf2f(p >> 16);
        sx += x; qx += x * x; sy += y; qy += y * y;
    }
    red[0][tid] = sx; red[1][tid] = qx; red[2][tid] = sy; red[3][tid] = qy;
    __syncthreads();
    // thread tid: stat s=tid>>6 over lane l=tid&63
    int s = tid >> 6, l = tid & 63;
    float v = red[s][l] + red[s][64 + l] + red[s][128 + l] + red[s][192 + l];
    // s=0: sum col 2l ; s=1: sumsq col 2l ; s=2: sum col 2l+1 ; s=3: sumsq col 2l+1
    atomicAdd(&sums[(s & 1) * 128 + 2 * l + (s >> 1)], v);
}

// ---------------- Layer-3 readout: MFMA, out += bnrelu(h3) @ WfT-slice2 ----------------

__global__ __launch_bounds__(256) void k_out_mfma(const unsigned short* __restrict__ h,
                                                  const unsigned short* __restrict__ WfT,
                                                  float* __restrict__ outp,
                                                  const float* __restrict__ sums,
                                                  const float* __restrict__ g,
                                                  const float* __restrict__ be) {
    __shared__ unsigned short As[128 * 128];  // 32 KB
    int tid = threadIdx.x;
    int row0 = blockIdx.x * 128;

    int c8 = tid & 15, cc = c8 * 8;
    float s8[8], t8[8];
#pragma unroll
    for (int u = 0; u < 8; ++u) {
        float mean = sums[cc + u] * (1.0f / N_NODES);
        float var = fmaxf(sums[128 + cc + u] * (1.0f / N_NODES) - mean * mean, 0.f);
        float s = g[cc + u] * rsqrtf(var + BN_EPS);
        s8[u] = s;
        t8[u] = be[cc + u] - mean * s;
    }
    const uint4* H4 = (const uint4*)h;
#pragma unroll
    for (int i = 0; i < 8; ++i) {
        int idx = i * 256 + tid;
        int r = idx >> 4;
        int gr = row0 + r;
        uint4 v = make_uint4(0, 0, 0, 0);
        if (gr < N_NODES) v = H4[(size_t)gr * 16 + c8];
        uint32 w[4] = {v.x, v.y, v.z, v.w};
        uint32 o[4];
#pragma unroll
        for (int p = 0; p < 4; ++p) {
            float f0 = bf2f(w[p] & 0xFFFFu) * s8[2 * p] + t8[2 * p];
            float f1 = bf2f(w[p] >> 16) * s8[2 * p + 1] + t8[2 * p + 1];
            o[p] = pack_bf2(fmaxf(f0, 0.f), fmaxf(f1, 0.f));
        }
        int swz = c8 ^ (r & 15);
        *(uint4*)&As[r * 128 + swz * 8] = make_uint4(o[0], o[1], o[2], o[3]);
    }
    __syncthreads();

    int wave = tid >> 6, lane = tid & 63;
    int quad = lane >> 4, l16 = lane & 15;
    int m0 = wave * 32;

    f32x4 accO[2] = {(f32x4){0.f, 0.f, 0.f, 0.f}, (f32x4){0.f, 0.f, 0.f, 0.f}};
#pragma unroll
    for (int ks = 0; ks < 4; ++ks) {
        bf16x8 bw = *(const bf16x8*)&WfT[l16 * 128 + (ks * 4 + quad) * 8];
#pragma unroll
        for (int mt = 0; mt < 2; ++mt) {
            int m = m0 + mt * 16 + l16;
            int swz = (ks * 4 + quad) ^ (m & 15);
            bf16x8 av = *(bf16x8*)&As[m * 128 + swz * 8];
            accO[mt] = __builtin_amdgcn_mfma_f32_16x16x32_bf16(av, bw, accO[mt], 0, 0, 0);
        }
    }
    if (l16 < C_OUT) {
#pragma unroll
        for (int mt = 0; mt < 2; ++mt)
#pragma unroll
            for (int reg = 0; reg < 4; ++reg) {
                int m = row0 + m0 + mt * 16 + quad * 4 + reg;
                if (m < N_NODES)
                    outp[(size_t)m * C_OUT + l16] += accO[mt][reg];
            }
    }
}

// ---------------- launch ----------------

extern "C" void kernel_launch(void* const* d_in, const int* in_sizes, int n_in,
                              void* d_out, int out_size, void* d_ws, size_t ws_size,
                              hipStream_t stream) {
    const float* x  = (const float*)d_in[0];
    const int*   ei = (const int*)d_in[1];
    const float* W1 = (const float*)d_in[2];
    const float* W2 = (const float*)d_in[4];
    const float* W3 = (const float*)d_in[6];
    // b1/b2/b3 absorbed exactly by BN mean-subtraction
    const float* g1  = (const float*)d_in[8];
    const float* be1 = (const float*)d_in[9];
    const float* g2  = (const float*)d_in[10];
    const float* be2 = (const float*)d_in[11];
    const float* g3  = (const float*)d_in[12];
    const float* be3 = (const float*)d_in[13];
    const float* Wf  = (const float*)d_in[14];
    const float* bf  = (const float*)d_in[15];
    float* out = (float*)d_out;

    char* ws = (char*)d_ws;
    size_t off = 0;
    auto alloc = [&](size_t bytes) -> void* {
        void* p = ws + off;
        off = (off + bytes + 255) & ~(size_t)255;
        return p;
    };
    int*   head  = (int*)alloc((size_t)N_NODES * 4);
    int*   next  = (int*)alloc((size_t)N_EDGES * 4);
    int*   adj   = (int*)alloc((size_t)N_NODES * CAP * 4);   // 12.8 MB padded rows
    int*   cnt   = (int*)alloc((size_t)N_NODES * 4);
    float* dinv  = (float*)alloc((size_t)N_NODES * 4);
    float* sums  = (float*)alloc(768 * 4);
    unsigned short* WT   = (unsigned short*)alloc((size_t)3 * 128 * 128 * 2);
    unsigned short* WfT  = (unsigned short*)alloc((size_t)3 * 16 * 128 * 2);
    unsigned short* hl   = (unsigned short*)alloc((size_t)N_NODES * 128 * 2);  // bf16
    unsigned short* bufA = (unsigned short*)alloc((size_t)N_NODES * 128 * 2);  // bf16 agg
    unsigned short* bufB = (unsigned short*)alloc((size_t)N_NODES * 128 * 2);  // bf16 agg

    const int TPB = 256;
    k_prep<<<384, 128, 0, stream>>>(W1, W2, W3, WT);
    k_prepf<<<24, 256, 0, stream>>>(Wf, WfT);
    k_init<<<(N_NODES + TPB - 1) / TPB, TPB, 0, stream>>>(head, sums);
    k_link<<<(N_EDGES + TPB - 1) / TPB, TPB, 0, stream>>>(ei, head, next);
    k_walk<<<(N_NODES + TPB - 1) / TPB, TPB, 0, stream>>>(ei, head, next, adj, cnt, dinv);

    const int gemm_grid = (N_NODES + 127) / 128;        // 391
    const int agg_grid  = (N_NODES + 3) / 4;            // wave per node, 4/block

    // ---- layer 1 ----
    k_gemm<<<gemm_grid, 256, 0, stream>>>(x, nullptr, WT, hl, nullptr, nullptr, nullptr,
                                          dinv, nullptr, nullptr, nullptr, 0);
    k_agg<<<agg_grid, 256, 0, stream>>>(hl, adj, cnt, dinv, bufA);
    k_bn_stats<<<512, 256, 0, stream>>>(bufA, sums + 0);

    // ---- layer 2 (gemm also emits out = h1 @ Wf0 + bf) ----
    k_gemm<<<gemm_grid, 256, 0, stream>>>(nullptr, bufA, WT + 16384, hl, sums + 0, g1, be1,
                                          dinv, WfT, bf, out, 1);
    k_agg<<<agg_grid, 256, 0, stream>>>(hl, adj, cnt, dinv, bufB);
    k_bn_stats<<<512, 256, 0, stream>>>(bufB, sums + 256);

    // ---- layer 3 (gemm also emits out += h2 @ Wf1) ----
    k_gemm<<<gemm_grid, 256, 0, stream>>>(nullptr, bufB, WT + 32768, hl, sums + 256, g2, be2,
                                          dinv, WfT + 2048, nullptr, out, 2);
    k_agg<<<agg_grid, 256, 0, stream>>>(hl, adj, cnt, dinv, bufA);
    k_bn_stats<<<512, 256, 0, stream>>>(bufA, sums + 512);

    // ---- layer 3 readout (MFMA) ----
    k_out_mfma<<<gemm_grid, 256, 0, stream>>>(bufA, WfT + 4096, out, sums + 512, g3, be3);
}

// Round 10
// 414.886 us; speedup vs baseline: 1.8957x; 1.0269x over previous
//
#include <hip/hip_runtime.h>

#define N_NODES 50000
#define N_EDGES 800000
#define D 128
#define C_OUT 10
#define BN_EPS 1e-5f
#define CAP 64            // padded adjacency row capacity; P(deg>=63)~1e-17 (Poisson 16)
#define GEMM_GRID 391     // ceil(50000/128)
#define LINK_BLOCKS 3125  // 3125*256 == 800000 == N_EDGES exactly

typedef unsigned int uint32;
typedef __attribute__((ext_vector_type(8))) short bf16x8;
typedef __attribute__((ext_vector_type(4))) float f32x4;

__device__ __forceinline__ float bf2f(unsigned int u16) {
    unsigned int x = u16 << 16;
    float f;
    __builtin_memcpy(&f, &x, 4);
    return f;
}
__device__ __forceinline__ unsigned int f2bf(float f) {
    unsigned int x;
    __builtin_memcpy(&x, &f, 4);
    unsigned int r = x + 0x7FFFu + ((x >> 16) & 1u);  // RNE
    return r >> 16;
}
__device__ __forceinline__ uint32 pack_bf2(float a, float b) {
    return f2bf(a) | (f2bf(b) << 16);
}

// ---------------- setup: W^T bf16, Wf^T bf16, head init (64B-padded), sums=0 ----------

__global__ void k_setup(const float* __restrict__ W1, const float* __restrict__ W2,
                        const float* __restrict__ W3, const float* __restrict__ Wf,
                        unsigned short* __restrict__ WT, unsigned short* __restrict__ WfT,
                        int* __restrict__ head, float* __restrict__ sums) {
    int b = blockIdx.x, tid = threadIdx.x;
    if (b < 192) {                       // WT: 3 x 128 x 128
        int idx = b * 256 + tid;
        int mat = idx >> 14, rem = idx & 16383;
        int n = rem >> 7, k = rem & 127;
        const float* W = (mat == 0) ? W1 : ((mat == 1) ? W2 : W3);
        WT[idx] = (unsigned short)f2bf(W[k * 128 + n]);
    } else if (b < 216) {                // WfT: 3 slices x 16(n,pad) x 128(k)
        int idx = (b - 192) * 256 + tid;
        if (idx < 6144) {
            int li = idx >> 11, rem = idx & 2047;
            int n = rem >> 7, k = rem & 127;
            WfT[idx] = (n < C_OUT) ? (unsigned short)f2bf(Wf[(li * 128 + k) * C_OUT + n]) : 0;
        }
    } else {                             // head init + sums zero
        int i = (b - 216) * 256 + tid;
        if (i < N_NODES) head[i << 4] = -1;   // one head per 64B line (atomic de-contention)
        if (i < 768) sums[i] = 0.0f;
    }
}

// ---------------- chain walk: thread-per-node -> padded adj rows + cnt + dinv ----------

__global__ void k_walk(const int* __restrict__ ei, const int* __restrict__ head,
                       const int* __restrict__ next, int* __restrict__ adj,
                       int* __restrict__ cnt, float* __restrict__ dinv) {
    int i = blockIdx.x * blockDim.x + threadIdx.x;
    if (i >= N_NODES) return;
    int* row = adj + ((size_t)i << 6);
    row[0] = i;                                 // self loop first
    int j = 1;
    int e = head[i << 4];
    while (e >= 0 && j < CAP) {
        row[j++] = ei[e];                       // source id
        e = next[e];
    }
    cnt[i] = j;
    dinv[i] = rsqrtf((float)j);                 // deg = chain length + self
}

// ---------------- MFMA GEMM (+ optional fused link blocks, BN prologue, readout) ------
// hl[M,128](bf16, UNSCALED) = bnrelu(A) @ W. A: Af32 (layer1) XOR Abf (bf16, BN'd).
// If linkEi: blocks [0,LINK_BLOCKS) do the adjacency atomicExch build instead (indep).
// mode: 0=none, 1=out = staged@WfT + bias, 2=out += staged@WfT.

__global__ __launch_bounds__(256) void k_gemm(const float* __restrict__ Af32,
                                              const unsigned short* __restrict__ Abf,
                                              const unsigned short* __restrict__ WT,
                                              unsigned short* __restrict__ hl,
                                              const float* __restrict__ sums,
                                              const float* __restrict__ g,
                                              const float* __restrict__ be,
                                              const unsigned short* __restrict__ WfT,
                                              const float* __restrict__ bfv,
                                              float* __restrict__ outp, int mode,
                                              const int* __restrict__ linkEi,
                                              int* __restrict__ head,
                                              int* __restrict__ next) {
    __shared__ unsigned short As[128 * 128];  // 32 KB
    __shared__ unsigned short Ws[128 * 128];  // 32 KB
    int tid = threadIdx.x;
    int bid = blockIdx.x;

    if (linkEi) {
        if (bid < LINK_BLOCKS) {   // adjacency build: 1 atomic/edge, padded heads
            int e = bid * 256 + tid;              // exactly covers N_EDGES
            int d = linkEi[N_EDGES + e];
            next[e] = atomicExch(&head[d << 4], e);
            return;
        }
        bid -= LINK_BLOCKS;
    }
    int row0 = bid * 128;

    // stage Ws (bf16 W^T [n][k]); XOR swizzle in 16B blocks: 2-way conflicts max (free)
    const ushort4* WT4 = (const ushort4*)WT;
#pragma unroll
    for (int i = 0; i < 16; ++i) {
        int idx = i * 256 + tid;
        int r = idx >> 5, c4 = idx & 31;
        ushort4 v = WT4[idx];
        int swz = (c4 >> 1) ^ (r & 15);
        *(ushort4*)&Ws[r * 128 + swz * 8 + (c4 & 1) * 4] = v;
    }

    if (Abf) {
        // bf16 A path: thread stages 8 fixed columns cc..cc+7 (c8 = tid&15)
        int c8 = tid & 15, cc = c8 * 8;
        float s8[8], t8[8];
#pragma unroll
        for (int u = 0; u < 8; ++u) {
            float mean = sums[cc + u] * (1.0f / N_NODES);
            float var = fmaxf(sums[128 + cc + u] * (1.0f / N_NODES) - mean * mean, 0.f);
            float s = g[cc + u] * rsqrtf(var + BN_EPS);
            s8[u] = s;
            t8[u] = be[cc + u] - mean * s;
        }
        const uint4* H4 = (const uint4*)Abf;
#pragma unroll
        for (int i = 0; i < 8; ++i) {
            int idx = i * 256 + tid;
            int r = idx >> 4;                   // 0..127
            int gr = row0 + r;
            uint4 v = make_uint4(0, 0, 0, 0);
            if (gr < N_NODES) v = H4[(size_t)gr * 16 + c8];
            uint32 w[4] = {v.x, v.y, v.z, v.w};
            uint32 o[4];
#pragma unroll
            for (int p = 0; p < 4; ++p) {
                float f0 = bf2f(w[p] & 0xFFFFu) * s8[2 * p] + t8[2 * p];
                float f1 = bf2f(w[p] >> 16) * s8[2 * p + 1] + t8[2 * p + 1];
                o[p] = pack_bf2(fmaxf(f0, 0.f), fmaxf(f1, 0.f));
            }
            int swz = c8 ^ (r & 15);
            *(uint4*)&As[r * 128 + swz * 8] = make_uint4(o[0], o[1], o[2], o[3]);
        }
    } else {
        // fp32 A path (layer 1: x, no BN)
        const float4* A4 = (const float4*)Af32;
#pragma unroll
        for (int i = 0; i < 16; ++i) {
            int idx = i * 256 + tid;
            int r = idx >> 5, c4 = idx & 31;
            int gr = row0 + r;
            float4 v = make_float4(0.f, 0.f, 0.f, 0.f);
            if (gr < N_NODES) v = A4[(size_t)gr * 32 + c4];
            ushort4 o;
            o.x = (unsigned short)f2bf(v.x);
            o.y = (unsigned short)f2bf(v.y);
            o.z = (unsigned short)f2bf(v.z);
            o.w = (unsigned short)f2bf(v.w);
            int swz = (c4 >> 1) ^ (r & 15);
            *(ushort4*)&As[r * 128 + swz * 8 + (c4 & 1) * 4] = o;
        }
    }
    __syncthreads();

    int wave = tid >> 6, lane = tid & 63;
    int quad = lane >> 4, l16 = lane & 15;
    int m0 = wave * 32;

    // a-frags: A[m=lane&15][k = ks*32 + quad*8 + j]
    bf16x8 af[2][4];
#pragma unroll
    for (int mt = 0; mt < 2; ++mt) {
        int m = m0 + mt * 16 + l16;
#pragma unroll
        for (int ks = 0; ks < 4; ++ks) {
            int swz = (ks * 4 + quad) ^ (m & 15);
            af[mt][ks] = *(bf16x8*)&As[m * 128 + swz * 8];
        }
    }

    f32x4 acc[8][2];
#pragma unroll
    for (int nt = 0; nt < 8; ++nt)
#pragma unroll
        for (int mt = 0; mt < 2; ++mt) acc[nt][mt] = (f32x4){0.f, 0.f, 0.f, 0.f};

#pragma unroll
    for (int nt = 0; nt < 8; ++nt) {
        int n = nt * 16 + l16;
        bf16x8 bfr[4];
#pragma unroll
        for (int ks = 0; ks < 4; ++ks) {
            int swz = (ks * 4 + quad) ^ (n & 15);
            bfr[ks] = *(bf16x8*)&Ws[n * 128 + swz * 8];
        }
#pragma unroll
        for (int mt = 0; mt < 2; ++mt)
#pragma unroll
            for (int ks = 0; ks < 4; ++ks)
                acc[nt][mt] = __builtin_amdgcn_mfma_f32_16x16x32_bf16(
                    af[mt][ks], bfr[ks], acc[nt][mt], 0, 0, 0);
    }

    // fused readout partial: out (=|+=) staged @ WfT (+bias). 8 extra MFMAs.
    if (mode != 0) {
        f32x4 accO[2] = {(f32x4){0.f, 0.f, 0.f, 0.f}, (f32x4){0.f, 0.f, 0.f, 0.f}};
#pragma unroll
        for (int ks = 0; ks < 4; ++ks) {
            int chunk = ks * 4 + quad;
            bf16x8 bw = *(const bf16x8*)&WfT[l16 * 128 + chunk * 8];  // tiny, L2-hot
            accO[0] = __builtin_amdgcn_mfma_f32_16x16x32_bf16(af[0][ks], bw, accO[0], 0, 0, 0);
            accO[1] = __builtin_amdgcn_mfma_f32_16x16x32_bf16(af[1][ks], bw, accO[1], 0, 0, 0);
        }
        if (l16 < C_OUT) {
#pragma unroll
            for (int mt = 0; mt < 2; ++mt)
#pragma unroll
                for (int reg = 0; reg < 4; ++reg) {
                    int m = row0 + m0 + mt * 16 + quad * 4 + reg;
                    if (m < N_NODES) {
                        size_t o = (size_t)m * C_OUT + l16;
                        float v = accO[mt][reg];
                        if (mode == 1) outp[o] = v + bfv[l16];
                        else outp[o] += v;
                    }
                }
        }
    }

    // C/D: col = lane&15, row = quad*4 + reg; store bf16 (unscaled; agg applies dinv)
#pragma unroll
    for (int mt = 0; mt < 2; ++mt) {
#pragma unroll
        for (int reg = 0; reg < 4; ++reg) {
            int m = row0 + m0 + mt * 16 + quad * 4 + reg;
            if (m < N_NODES) {
#pragma unroll
                for (int nt = 0; nt < 8; ++nt) {
                    int n = nt * 16 + l16;
                    hl[(size_t)m * 128 + n] = (unsigned short)f2bf(acc[nt][mt][reg]);
                }
            }
        }
    }
}

// ---------------- Aggregation: wave/node, unroll-8 MLP, per-edge dinv, bf16 out --------

__global__ void k_agg(const unsigned short* __restrict__ hl, const int* __restrict__ adj,
                      const int* __restrict__ cnt, const float* __restrict__ dinv,
                      unsigned short* __restrict__ agg) {
    int node = (int)((blockIdx.x * blockDim.x + threadIdx.x) >> 6);
    int lane = threadIdx.x & 63;
    if (node >= N_NODES) return;
    const int* row = adj + ((size_t)node << 6);   // wave-uniform scalar reads
    int n = cnt[node];
    float ax = 0.f, ay = 0.f;
    int e = 0;
    for (; e + 7 < n; e += 8) {
        int j[8];
#pragma unroll
        for (int u = 0; u < 8; ++u) j[u] = row[e + u];
        float w[8];
        uint32 p[8];
#pragma unroll
        for (int u = 0; u < 8; ++u) {
            w[u] = dinv[j[u]];
            p[u] = *(const uint32*)&hl[(size_t)j[u] * 128 + lane * 2];
        }
#pragma unroll
        for (int u = 0; u < 8; ++u) {
            ax += bf2f(p[u] & 0xFFFFu) * w[u];
            ay += bf2f(p[u] >> 16) * w[u];
        }
    }
    for (; e < n; ++e) {
        int j = row[e];
        float w = dinv[j];
        uint32 p = *(const uint32*)&hl[(size_t)j * 128 + lane * 2];
        ax += bf2f(p & 0xFFFFu) * w;
        ay += bf2f(p >> 16) * w;
    }
    float di = dinv[node];
    *(uint32*)&agg[(size_t)node * 128 + lane * 2] = pack_bf2(ax * di, ay * di);
}

// ---------------- BN stats over bf16 agg (uint32/lane, 4-wave LDS reduce) ----------------

__global__ __launch_bounds__(256) void k_bn_stats(const unsigned short* __restrict__ agg,
                                                  float* __restrict__ sums) {
    __shared__ float red[4][256];
    int tid = threadIdx.x;
    int lane = tid & 63, w = tid >> 6;
    float sx = 0.f, qx = 0.f, sy = 0.f, qy = 0.f;
    for (int r = blockIdx.x * 4 + w; r < N_NODES; r += gridDim.x * 4) {
        uint32 p = *(const uint32*)&agg[(size_t)r * 128 + lane * 2];
        float x = bf2f(p & 0xFFFFu), y = bf2f(p >> 16);
        sx += x; qx += x * x; sy += y; qy += y * y;
    }
    red[0][tid] = sx; red[1][tid] = qx; red[2][tid] = sy; red[3][tid] = qy;
    __syncthreads();
    int s = tid >> 6, l = tid & 63;
    float v = red[s][l] + red[s][64 + l] + red[s][128 + l] + red[s][192 + l];
    atomicAdd(&sums[(s & 1) * 128 + 2 * l + (s >> 1)], v);
}

// ---------------- Layer-3 readout: MFMA, out += bnrelu(h3) @ WfT-slice2 ----------------

__global__ __launch_bounds__(256) void k_out_mfma(const unsigned short* __restrict__ h,
                                                  const unsigned short* __restrict__ WfT,
                                                  float* __restrict__ outp,
                                                  const float* __restrict__ sums,
                                                  const float* __restrict__ g,
                                                  const float* __restrict__ be) {
    __shared__ unsigned short As[128 * 128];  // 32 KB
    int tid = threadIdx.x;
    int row0 = blockIdx.x * 128;

    int c8 = tid & 15, cc = c8 * 8;
    float s8[8], t8[8];
#pragma unroll
    for (int u = 0; u < 8; ++u) {
        float mean = sums[cc + u] * (1.0f / N_NODES);
        float var = fmaxf(sums[128 + cc + u] * (1.0f / N_NODES) - mean * mean, 0.f);
        float s = g[cc + u] * rsqrtf(var + BN_EPS);
        s8[u] = s;
        t8[u] = be[cc + u] - mean * s;
    }
    const uint4* H4 = (const uint4*)h;
#pragma unroll
    for (int i = 0; i < 8; ++i) {
        int idx = i * 256 + tid;
        int r = idx >> 4;
        int gr = row0 + r;
        uint4 v = make_uint4(0, 0, 0, 0);
        if (gr < N_NODES) v = H4[(size_t)gr * 16 + c8];
        uint32 w[4] = {v.x, v.y, v.z, v.w};
        uint32 o[4];
#pragma unroll
        for (int p = 0; p < 4; ++p) {
            float f0 = bf2f(w[p] & 0xFFFFu) * s8[2 * p] + t8[2 * p];
            float f1 = bf2f(w[p] >> 16) * s8[2 * p + 1] + t8[2 * p + 1];
            o[p] = pack_bf2(fmaxf(f0, 0.f), fmaxf(f1, 0.f));
        }
        int swz = c8 ^ (r & 15);
        *(uint4*)&As[r * 128 + swz * 8] = make_uint4(o[0], o[1], o[2], o[3]);
    }
    __syncthreads();

    int wave = tid >> 6, lane = tid & 63;
    int quad = lane >> 4, l16 = lane & 15;
    int m0 = wave * 32;

    f32x4 accO[2] = {(f32x4){0.f, 0.f, 0.f, 0.f}, (f32x4){0.f, 0.f, 0.f, 0.f}};
#pragma unroll
    for (int ks = 0; ks < 4; ++ks) {
        bf16x8 bw = *(const bf16x8*)&WfT[l16 * 128 + (ks * 4 + quad) * 8];
#pragma unroll
        for (int mt = 0; mt < 2; ++mt) {
            int m = m0 + mt * 16 + l16;
            int swz = (ks * 4 + quad) ^ (m & 15);
            bf16x8 av = *(bf16x8*)&As[m * 128 + swz * 8];
            accO[mt] = __builtin_amdgcn_mfma_f32_16x16x32_bf16(av, bw, accO[mt], 0, 0, 0);
        }
    }
    if (l16 < C_OUT) {
#pragma unroll
        for (int mt = 0; mt < 2; ++mt)
#pragma unroll
            for (int reg = 0; reg < 4; ++reg) {
                int m = row0 + m0 + mt * 16 + quad * 4 + reg;
                if (m < N_NODES)
                    outp[(size_t)m * C_OUT + l16] += accO[mt][reg];
            }
    }
}

// ---------------- launch ----------------

extern "C" void kernel_launch(void* const* d_in, const int* in_sizes, int n_in,
                              void* d_out, int out_size, void* d_ws, size_t ws_size,
                              hipStream_t stream) {
    const float* x  = (const float*)d_in[0];
    const int*   ei = (const int*)d_in[1];
    const float* W1 = (const float*)d_in[2];
    const float* W2 = (const float*)d_in[4];
    const float* W3 = (const float*)d_in[6];
    // b1/b2/b3 absorbed exactly by BN mean-subtraction
    const float* g1  = (const float*)d_in[8];
    const float* be1 = (const float*)d_in[9];
    const float* g2  = (const float*)d_in[10];
    const float* be2 = (const float*)d_in[11];
    const float* g3  = (const float*)d_in[12];
    const float* be3 = (const float*)d_in[13];
    const float* Wf  = (const float*)d_in[14];
    const float* bf  = (const float*)d_in[15];
    float* out = (float*)d_out;

    char* ws = (char*)d_ws;
    size_t off = 0;
    auto alloc = [&](size_t bytes) -> void* {
        void* p = ws + off;
        off = (off + bytes + 255) & ~(size_t)255;
        return p;
    };
    int*   head  = (int*)alloc((size_t)N_NODES * 16 * 4);    // 64B-padded heads, 3.2MB
    int*   next  = (int*)alloc((size_t)N_EDGES * 4);
    int*   adj   = (int*)alloc((size_t)N_NODES * CAP * 4);   // 12.8 MB padded rows
    int*   cnt   = (int*)alloc((size_t)N_NODES * 4);
    float* dinv  = (float*)alloc((size_t)N_NODES * 4);
    float* sums  = (float*)alloc(768 * 4);
    unsigned short* WT   = (unsigned short*)alloc((size_t)3 * 128 * 128 * 2);
    unsigned short* WfT  = (unsigned short*)alloc((size_t)3 * 16 * 128 * 2);
    unsigned short* hl   = (unsigned short*)alloc((size_t)N_NODES * 128 * 2);  // bf16
    unsigned short* bufA = (unsigned short*)alloc((size_t)N_NODES * 128 * 2);  // bf16 agg
    unsigned short* bufB = (unsigned short*)alloc((size_t)N_NODES * 128 * 2);  // bf16 agg

    const int TPB = 256;
    k_setup<<<412, 256, 0, stream>>>(W1, W2, W3, Wf, WT, WfT, head, sums);

    const int agg_grid = (N_NODES + 3) / 4;            // wave per node, 4/block

    // ---- layer 1 GEMM fused with adjacency link build (independent work) ----
    k_gemm<<<LINK_BLOCKS + GEMM_GRID, 256, 0, stream>>>(
        x, nullptr, WT, hl, nullptr, nullptr, nullptr,
        nullptr, nullptr, nullptr, 0, ei, head, next);
    k_walk<<<(N_NODES + TPB - 1) / TPB, TPB, 0, stream>>>(ei, head, next, adj, cnt, dinv);
    k_agg<<<agg_grid, 256, 0, stream>>>(hl, adj, cnt, dinv, bufA);
    k_bn_stats<<<512, 256, 0, stream>>>(bufA, sums + 0);

    // ---- layer 2 (gemm also emits out = h1 @ Wf0 + bf) ----
    k_gemm<<<GEMM_GRID, 256, 0, stream>>>(nullptr, bufA, WT + 16384, hl, sums + 0, g1, be1,
                                          WfT, bf, out, 1, nullptr, nullptr, nullptr);
    k_agg<<<agg_grid, 256, 0, stream>>>(hl, adj, cnt, dinv, bufB);
    k_bn_stats<<<512, 256, 0, stream>>>(bufB, sums + 256);

    // ---- layer 3 (gemm also emits out += h2 @ Wf1) ----
    k_gemm<<<GEMM_GRID, 256, 0, stream>>>(nullptr, bufB, WT + 32768, hl, sums + 256, g2, be2,
                                          WfT + 2048, nullptr, out, 2, nullptr, nullptr, nullptr);
    k_agg<<<agg_grid, 256, 0, stream>>>(hl, adj, cnt, dinv, bufA);
    k_bn_stats<<<512, 256, 0, stream>>>(bufA, sums + 512);

    // ---- layer 3 readout (MFMA) ----
    k_out_mfma<<<GEMM_GRID, 256, 0, stream>>>(bufA, WfT + 4096, out, sums + 512, g3, be3);
}

// Round 11
// 413.025 us; speedup vs baseline: 1.9043x; 1.0045x over previous
//
#include <hip/hip_runtime.h>

#define N_NODES 50000
#define N_EDGES 800000
#define D 128
#define C_OUT 10
#define BN_EPS 1e-5f
#define CAP 64            // padded adjacency row capacity; P(deg>=63)~1e-17 (Poisson 16)
#define GEMM_GRID 391     // ceil(50000/128)
#define LINK_BLOCKS 3125  // 3125*256 == 800000 == N_EDGES exactly
#define CSTR 136          // LDS C-dump row stride (ushorts): quad writes 2-way max

typedef unsigned int uint32;
typedef __attribute__((ext_vector_type(8))) short bf16x8;
typedef __attribute__((ext_vector_type(4))) float f32x4;

__device__ __forceinline__ float bf2f(unsigned int u16) {
    unsigned int x = u16 << 16;
    float f;
    __builtin_memcpy(&f, &x, 4);
    return f;
}
__device__ __forceinline__ unsigned int f2bf(float f) {
    unsigned int x;
    __builtin_memcpy(&x, &f, 4);
    unsigned int r = x + 0x7FFFu + ((x >> 16) & 1u);  // RNE
    return r >> 16;
}
__device__ __forceinline__ uint32 pack_bf2(float a, float b) {
    return f2bf(a) | (f2bf(b) << 16);
}

// ---------------- setup: W^T bf16, Wf^T bf16, head init (64B-padded), sums=0 ----------

__global__ void k_setup(const float* __restrict__ W1, const float* __restrict__ W2,
                        const float* __restrict__ W3, const float* __restrict__ Wf,
                        unsigned short* __restrict__ WT, unsigned short* __restrict__ WfT,
                        int* __restrict__ head, float* __restrict__ sums) {
    int b = blockIdx.x, tid = threadIdx.x;
    if (b < 192) {                       // WT: 3 x 128 x 128
        int idx = b * 256 + tid;
        int mat = idx >> 14, rem = idx & 16383;
        int n = rem >> 7, k = rem & 127;
        const float* W = (mat == 0) ? W1 : ((mat == 1) ? W2 : W3);
        WT[idx] = (unsigned short)f2bf(W[k * 128 + n]);
    } else if (b < 216) {                // WfT: 3 slices x 16(n,pad) x 128(k)
        int idx = (b - 192) * 256 + tid;
        if (idx < 6144) {
            int li = idx >> 11, rem = idx & 2047;
            int n = rem >> 7, k = rem & 127;
            WfT[idx] = (n < C_OUT) ? (unsigned short)f2bf(Wf[(li * 128 + k) * C_OUT + n]) : 0;
        }
    } else {                             // head init + sums zero
        int i = (b - 216) * 256 + tid;
        if (i < N_NODES) head[i << 4] = -1;   // one head per 64B line (atomic de-contention)
        if (i < 768) sums[i] = 0.0f;
    }
}

// ---------------- chain walk: thread-per-node -> padded adj rows + cnt + dinv ----------

__global__ void k_walk(const int* __restrict__ ei, const int* __restrict__ head,
                       const int* __restrict__ next, int* __restrict__ adj,
                       int* __restrict__ cnt, float* __restrict__ dinv) {
    int i = blockIdx.x * blockDim.x + threadIdx.x;
    if (i >= N_NODES) return;
    int* row = adj + ((size_t)i << 6);
    row[0] = i;                                 // self loop first
    int j = 1;
    int e = head[i << 4];
    while (e >= 0 && j < CAP) {
        row[j++] = ei[e];                       // source id
        e = next[e];
    }
    cnt[i] = j;
    dinv[i] = rsqrtf((float)j);                 // deg = chain length + self
}

// ---------------- MFMA GEMM (+ optional fused link blocks, BN prologue, readout) ------
// hl[M,128](bf16, UNSCALED) = bnrelu(A) @ W. A: Af32 (layer1) XOR Abf (bf16, BN'd).
// C-tile goes acc -> LDS (bf16) -> coalesced uint4 global store (R10: direct 2B
// scattered stores caused 3.2x HBM write amplification, 40.6MB vs 12.8MB).
// If linkEi: blocks [0,LINK_BLOCKS) do the adjacency atomicExch build instead.
// mode: 0=none, 1=out = staged@WfT + bias, 2=out += staged@WfT.

__global__ __launch_bounds__(256) void k_gemm(const float* __restrict__ Af32,
                                              const unsigned short* __restrict__ Abf,
                                              const unsigned short* __restrict__ WT,
                                              unsigned short* __restrict__ hl,
                                              const float* __restrict__ sums,
                                              const float* __restrict__ g,
                                              const float* __restrict__ be,
                                              const unsigned short* __restrict__ WfT,
                                              const float* __restrict__ bfv,
                                              float* __restrict__ outp, int mode,
                                              const int* __restrict__ linkEi,
                                              int* __restrict__ head,
                                              int* __restrict__ next) {
    __shared__ unsigned short SM[32768];      // 64 KB: As=SM[0:16384), Ws=SM[16384:32768)
    unsigned short* As = SM;
    unsigned short* Ws = SM + 16384;
    int tid = threadIdx.x;
    int bid = blockIdx.x;

    if (linkEi) {
        if (bid < LINK_BLOCKS) {   // adjacency build: 1 atomic/edge, padded heads
            int e = bid * 256 + tid;              // exactly covers N_EDGES
            int d = linkEi[N_EDGES + e];
            next[e] = atomicExch(&head[d << 4], e);
            return;
        }
        bid -= LINK_BLOCKS;
    }
    int row0 = bid * 128;

    // stage Ws (bf16 W^T [n][k]); XOR swizzle in 16B blocks: 2-way conflicts max (free)
    const ushort4* WT4 = (const ushort4*)WT;
#pragma unroll
    for (int i = 0; i < 16; ++i) {
        int idx = i * 256 + tid;
        int r = idx >> 5, c4 = idx & 31;
        ushort4 v = WT4[idx];
        int swz = (c4 >> 1) ^ (r & 15);
        *(ushort4*)&Ws[r * 128 + swz * 8 + (c4 & 1) * 4] = v;
    }

    if (Abf) {
        // bf16 A path: thread stages 8 fixed columns cc..cc+7 (c8 = tid&15)
        int c8 = tid & 15, cc = c8 * 8;
        float s8[8], t8[8];
#pragma unroll
        for (int u = 0; u < 8; ++u) {
            float mean = sums[cc + u] * (1.0f / N_NODES);
            float var = fmaxf(sums[128 + cc + u] * (1.0f / N_NODES) - mean * mean, 0.f);
            float s = g[cc + u] * rsqrtf(var + BN_EPS);
            s8[u] = s;
            t8[u] = be[cc + u] - mean * s;
        }
        const uint4* H4 = (const uint4*)Abf;
#pragma unroll
        for (int i = 0; i < 8; ++i) {
            int idx = i * 256 + tid;
            int r = idx >> 4;                   // 0..127
            int gr = row0 + r;
            uint4 v = make_uint4(0, 0, 0, 0);
            if (gr < N_NODES) v = H4[(size_t)gr * 16 + c8];
            uint32 w[4] = {v.x, v.y, v.z, v.w};
            uint32 o[4];
#pragma unroll
            for (int p = 0; p < 4; ++p) {
                float f0 = bf2f(w[p] & 0xFFFFu) * s8[2 * p] + t8[2 * p];
                float f1 = bf2f(w[p] >> 16) * s8[2 * p + 1] + t8[2 * p + 1];
                o[p] = pack_bf2(fmaxf(f0, 0.f), fmaxf(f1, 0.f));
            }
            int swz = c8 ^ (r & 15);
            *(uint4*)&As[r * 128 + swz * 8] = make_uint4(o[0], o[1], o[2], o[3]);
        }
    } else {
        // fp32 A path (layer 1: x, no BN)
        const float4* A4 = (const float4*)Af32;
#pragma unroll
        for (int i = 0; i < 16; ++i) {
            int idx = i * 256 + tid;
            int r = idx >> 5, c4 = idx & 31;
            int gr = row0 + r;
            float4 v = make_float4(0.f, 0.f, 0.f, 0.f);
            if (gr < N_NODES) v = A4[(size_t)gr * 32 + c4];
            ushort4 o;
            o.x = (unsigned short)f2bf(v.x);
            o.y = (unsigned short)f2bf(v.y);
            o.z = (unsigned short)f2bf(v.z);
            o.w = (unsigned short)f2bf(v.w);
            int swz = (c4 >> 1) ^ (r & 15);
            *(ushort4*)&As[r * 128 + swz * 8 + (c4 & 1) * 4] = o;
        }
    }
    __syncthreads();

    int wave = tid >> 6, lane = tid & 63;
    int quad = lane >> 4, l16 = lane & 15;
    int m0 = wave * 32;

    // a-frags: A[m=lane&15][k = ks*32 + quad*8 + j]
    bf16x8 af[2][4];
#pragma unroll
    for (int mt = 0; mt < 2; ++mt) {
        int m = m0 + mt * 16 + l16;
#pragma unroll
        for (int ks = 0; ks < 4; ++ks) {
            int swz = (ks * 4 + quad) ^ (m & 15);
            af[mt][ks] = *(bf16x8*)&As[m * 128 + swz * 8];
        }
    }

    f32x4 acc[8][2];
#pragma unroll
    for (int nt = 0; nt < 8; ++nt)
#pragma unroll
        for (int mt = 0; mt < 2; ++mt) acc[nt][mt] = (f32x4){0.f, 0.f, 0.f, 0.f};

#pragma unroll
    for (int nt = 0; nt < 8; ++nt) {
        int n = nt * 16 + l16;
        bf16x8 bfr[4];
#pragma unroll
        for (int ks = 0; ks < 4; ++ks) {
            int swz = (ks * 4 + quad) ^ (n & 15);
            bfr[ks] = *(bf16x8*)&Ws[n * 128 + swz * 8];
        }
#pragma unroll
        for (int mt = 0; mt < 2; ++mt)
#pragma unroll
            for (int ks = 0; ks < 4; ++ks)
                acc[nt][mt] = __builtin_amdgcn_mfma_f32_16x16x32_bf16(
                    af[mt][ks], bfr[ks], acc[nt][mt], 0, 0, 0);
    }

    // fused readout partial: out (=|+=) staged @ WfT (+bias). 8 extra MFMAs.
    if (mode != 0) {
        f32x4 accO[2] = {(f32x4){0.f, 0.f, 0.f, 0.f}, (f32x4){0.f, 0.f, 0.f, 0.f}};
#pragma unroll
        for (int ks = 0; ks < 4; ++ks) {
            int chunk = ks * 4 + quad;
            bf16x8 bw = *(const bf16x8*)&WfT[l16 * 128 + chunk * 8];  // tiny, L2-hot
            accO[0] = __builtin_amdgcn_mfma_f32_16x16x32_bf16(af[0][ks], bw, accO[0], 0, 0, 0);
            accO[1] = __builtin_amdgcn_mfma_f32_16x16x32_bf16(af[1][ks], bw, accO[1], 0, 0, 0);
        }
        if (l16 < C_OUT) {
#pragma unroll
            for (int mt = 0; mt < 2; ++mt)
#pragma unroll
                for (int reg = 0; reg < 4; ++reg) {
                    int m = row0 + m0 + mt * 16 + quad * 4 + reg;
                    if (m < N_NODES) {
                        size_t o = (size_t)m * C_OUT + l16;
                        float v = accO[mt][reg];
                        if (mode == 1) outp[o] = v + bfv[l16];
                        else outp[o] += v;
                    }
                }
        }
    }

    // C-tile: acc -> LDS (bf16, stride CSTR) -> coalesced uint4 stores (full lines)
    __syncthreads();   // all waves done reading As/Ws
#pragma unroll
    for (int mt = 0; mt < 2; ++mt) {
#pragma unroll
        for (int reg = 0; reg < 4; ++reg) {
            int lm = m0 + mt * 16 + quad * 4 + reg;    // local row 0..127
#pragma unroll
            for (int nt = 0; nt < 8; ++nt)
                SM[lm * CSTR + nt * 16 + l16] = (unsigned short)f2bf(acc[nt][mt][reg]);
        }
    }
    __syncthreads();
    uint4* H4o = (uint4*)hl;
#pragma unroll
    for (int i = 0; i < 8; ++i) {
        int idx = i * 256 + tid;
        int r = idx >> 4, c8 = idx & 15;
        int gr = row0 + r;
        if (gr < N_NODES)
            H4o[(size_t)gr * 16 + c8] = *(uint4*)&SM[r * CSTR + c8 * 8];
    }
}

// ---------------- Aggregation: wave/node, unroll-8 MLP, per-edge dinv, bf16 out --------

__global__ void k_agg(const unsigned short* __restrict__ hl, const int* __restrict__ adj,
                      const int* __restrict__ cnt, const float* __restrict__ dinv,
                      unsigned short* __restrict__ agg) {
    int node = (int)((blockIdx.x * blockDim.x + threadIdx.x) >> 6);
    int lane = threadIdx.x & 63;
    if (node >= N_NODES) return;
    const int* row = adj + ((size_t)node << 6);   // wave-uniform scalar reads
    int n = cnt[node];
    float ax = 0.f, ay = 0.f;
    int e = 0;
    for (; e + 7 < n; e += 8) {
        int j[8];
#pragma unroll
        for (int u = 0; u < 8; ++u) j[u] = row[e + u];
        float w[8];
        uint32 p[8];
#pragma unroll
        for (int u = 0; u < 8; ++u) {
            w[u] = dinv[j[u]];
            p[u] = *(const uint32*)&hl[(size_t)j[u] * 128 + lane * 2];
        }
#pragma unroll
        for (int u = 0; u < 8; ++u) {
            ax += bf2f(p[u] & 0xFFFFu) * w[u];
            ay += bf2f(p[u] >> 16) * w[u];
        }
    }
    for (; e < n; ++e) {
        int j = row[e];
        float w = dinv[j];
        uint32 p = *(const uint32*)&hl[(size_t)j * 128 + lane * 2];
        ax += bf2f(p & 0xFFFFu) * w;
        ay += bf2f(p >> 16) * w;
    }
    float di = dinv[node];
    *(uint32*)&agg[(size_t)node * 128 + lane * 2] = pack_bf2(ax * di, ay * di);
}

// ---------------- BN stats over bf16 agg (uint32/lane, 4-wave LDS reduce) ----------------

__global__ __launch_bounds__(256) void k_bn_stats(const unsigned short* __restrict__ agg,
                                                  float* __restrict__ sums) {
    __shared__ float red[4][256];
    int tid = threadIdx.x;
    int lane = tid & 63, w = tid >> 6;
    float sx = 0.f, qx = 0.f, sy = 0.f, qy = 0.f;
    for (int r = blockIdx.x * 4 + w; r < N_NODES; r += gridDim.x * 4) {
        uint32 p = *(const uint32*)&agg[(size_t)r * 128 + lane * 2];
        float x = bf2f(p & 0xFFFFu), y = bf2f(p >> 16);
        sx += x; qx += x * x; sy += y; qy += y * y;
    }
    red[0][tid] = sx; red[1][tid] = qx; red[2][tid] = sy; red[3][tid] = qy;
    __syncthreads();
    int s = tid >> 6, l = tid & 63;
    float v = red[s][l] + red[s][64 + l] + red[s][128 + l] + red[s][192 + l];
    atomicAdd(&sums[(s & 1) * 128 + 2 * l + (s >> 1)], v);
}

// ---------------- Layer-3 readout: MFMA, out += bnrelu(h3) @ WfT-slice2 ----------------

__global__ __launch_bounds__(256) void k_out_mfma(const unsigned short* __restrict__ h,
                                                  const unsigned short* __restrict__ WfT,
                                                  float* __restrict__ outp,
                                                  const float* __restrict__ sums,
                                                  const float* __restrict__ g,
                                                  const float* __restrict__ be) {
    __shared__ unsigned short As[128 * 128];  // 32 KB
    int tid = threadIdx.x;
    int row0 = blockIdx.x * 128;

    int c8 = tid & 15, cc = c8 * 8;
    float s8[8], t8[8];
#pragma unroll
    for (int u = 0; u < 8; ++u) {
        float mean = sums[cc + u] * (1.0f / N_NODES);
        float var = fmaxf(sums[128 + cc + u] * (1.0f / N_NODES) - mean * mean, 0.f);
        float s = g[cc + u] * rsqrtf(var + BN_EPS);
        s8[u] = s;
        t8[u] = be[cc + u] - mean * s;
    }
    const uint4* H4 = (const uint4*)h;
#pragma unroll
    for (int i = 0; i < 8; ++i) {
        int idx = i * 256 + tid;
        int r = idx >> 4;
        int gr = row0 + r;
        uint4 v = make_uint4(0, 0, 0, 0);
        if (gr < N_NODES) v = H4[(size_t)gr * 16 + c8];
        uint32 w[4] = {v.x, v.y, v.z, v.w};
        uint32 o[4];
#pragma unroll
        for (int p = 0; p < 4; ++p) {
            float f0 = bf2f(w[p] & 0xFFFFu) * s8[2 * p] + t8[2 * p];
            float f1 = bf2f(w[p] >> 16) * s8[2 * p + 1] + t8[2 * p + 1];
            o[p] = pack_bf2(fmaxf(f0, 0.f), fmaxf(f1, 0.f));
        }
        int swz = c8 ^ (r & 15);
        *(uint4*)&As[r * 128 + swz * 8] = make_uint4(o[0], o[1], o[2], o[3]);
    }
    __syncthreads();

    int wave = tid >> 6, lane = tid & 63;
    int quad = lane >> 4, l16 = lane & 15;
    int m0 = wave * 32;

    f32x4 accO[2] = {(f32x4){0.f, 0.f, 0.f, 0.f}, (f32x4){0.f, 0.f, 0.f, 0.f}};
#pragma unroll
    for (int ks = 0; ks < 4; ++ks) {
        bf16x8 bw = *(const bf16x8*)&WfT[l16 * 128 + (ks * 4 + quad) * 8];
#pragma unroll
        for (int mt = 0; mt < 2; ++mt) {
            int m = m0 + mt * 16 + l16;
            int swz = (ks * 4 + quad) ^ (m & 15);
            bf16x8 av = *(bf16x8*)&As[m * 128 + swz * 8];
            accO[mt] = __builtin_amdgcn_mfma_f32_16x16x32_bf16(av, bw, accO[mt], 0, 0, 0);
        }
    }
    if (l16 < C_OUT) {
#pragma unroll
        for (int mt = 0; mt < 2; ++mt)
#pragma unroll
            for (int reg = 0; reg < 4; ++reg) {
                int m = row0 + m0 + mt * 16 + quad * 4 + reg;
                if (m < N_NODES)
                    outp[(size_t)m * C_OUT + l16] += accO[mt][reg];
            }
    }
}

// ---------------- launch ----------------

extern "C" void kernel_launch(void* const* d_in, const int* in_sizes, int n_in,
                              void* d_out, int out_size, void* d_ws, size_t ws_size,
                              hipStream_t stream) {
    const float* x  = (const float*)d_in[0];
    const int*   ei = (const int*)d_in[1];
    const float* W1 = (const float*)d_in[2];
    const float* W2 = (const float*)d_in[4];
    const float* W3 = (const float*)d_in[6];
    // b1/b2/b3 absorbed exactly by BN mean-subtraction
    const float* g1  = (const float*)d_in[8];
    const float* be1 = (const float*)d_in[9];
    const float* g2  = (const float*)d_in[10];
    const float* be2 = (const float*)d_in[11];
    const float* g3  = (const float*)d_in[12];
    const float* be3 = (const float*)d_in[13];
    const float* Wf  = (const float*)d_in[14];
    const float* bf  = (const float*)d_in[15];
    float* out = (float*)d_out;

    char* ws = (char*)d_ws;
    size_t off = 0;
    auto alloc = [&](size_t bytes) -> void* {
        void* p = ws + off;
        off = (off + bytes + 255) & ~(size_t)255;
        return p;
    };
    int*   head  = (int*)alloc((size_t)N_NODES * 16 * 4);    // 64B-padded heads, 3.2MB
    int*   next  = (int*)alloc((size_t)N_EDGES * 4);
    int*   adj   = (int*)alloc((size_t)N_NODES * CAP * 4);   // 12.8 MB padded rows
    int*   cnt   = (int*)alloc((size_t)N_NODES * 4);
    float* dinv  = (float*)alloc((size_t)N_NODES * 4);
    float* sums  = (float*)alloc(768 * 4);
    unsigned short* WT   = (unsigned short*)alloc((size_t)3 * 128 * 128 * 2);
    unsigned short* WfT  = (unsigned short*)alloc((size_t)3 * 16 * 128 * 2);
    unsigned short* hl   = (unsigned short*)alloc((size_t)N_NODES * 128 * 2);  // bf16
    unsigned short* bufA = (unsigned short*)alloc((size_t)N_NODES * 128 * 2);  // bf16 agg
    unsigned short* bufB = (unsigned short*)alloc((size_t)N_NODES * 128 * 2);  // bf16 agg

    const int TPB = 256;
    k_setup<<<412, 256, 0, stream>>>(W1, W2, W3, Wf, WT, WfT, head, sums);

    const int agg_grid = (N_NODES + 3) / 4;            // wave per node, 4/block

    // ---- layer 1 GEMM fused with adjacency link build (independent work) ----
    k_gemm<<<LINK_BLOCKS + GEMM_GRID, 256, 0, stream>>>(
        x, nullptr, WT, hl, nullptr, nullptr, nullptr,
        nullptr, nullptr, nullptr, 0, ei, head, next);
    k_walk<<<(N_NODES + TPB - 1) / TPB, TPB, 0, stream>>>(ei, head, next, adj, cnt, dinv);
    k_agg<<<agg_grid, 256, 0, stream>>>(hl, adj, cnt, dinv, bufA);
    k_bn_stats<<<512, 256, 0, stream>>>(bufA, sums + 0);

    // ---- layer 2 (gemm also emits out = h1 @ Wf0 + bf) ----
    k_gemm<<<GEMM_GRID, 256, 0, stream>>>(nullptr, bufA, WT + 16384, hl, sums + 0, g1, be1,
                                          WfT, bf, out, 1, nullptr, nullptr, nullptr);
    k_agg<<<agg_grid, 256, 0, stream>>>(hl, adj, cnt, dinv, bufB);
    k_bn_stats<<<512, 256, 0, stream>>>(bufB, sums + 256);

    // ---- layer 3 (gemm also emits out += h2 @ Wf1) ----
    k_gemm<<<GEMM_GRID, 256, 0, stream>>>(nullptr, bufB, WT + 32768, hl, sums + 256, g2, be2,
                                          WfT + 2048, nullptr, out, 2, nullptr, nullptr, nullptr);
    k_agg<<<agg_grid, 256, 0, stream>>>(hl, adj, cnt, dinv, bufA);
    k_bn_stats<<<512, 256, 0, stream>>>(bufA, sums + 512);

    // ---- layer 3 readout (MFMA) ----
    k_out_mfma<<<GEMM_GRID, 256, 0, stream>>>(bufA, WfT + 4096, out, sums + 512, g3, be3);
}